// Round 5
// baseline (2718.431 us; speedup 1.0000x reference)
//
#include <hip/hip_runtime.h>
#include <hip/hip_bf16.h>

typedef __attribute__((ext_vector_type(4))) float f32x4;
typedef __attribute__((ext_vector_type(8))) __bf16 bf16x8;
typedef unsigned short u16;
typedef __attribute__((ext_vector_type(4))) unsigned short u16x4;

__device__ __forceinline__ u16 f2bf(float f) {
  __bf16 h = (__bf16)f;
  return __builtin_bit_cast(u16, h);
}

__device__ __forceinline__ bf16x8 cvt2(f32x4 x, f32x4 y) {
  bf16x8 r;
  r[0] = (__bf16)x[0]; r[1] = (__bf16)x[1]; r[2] = (__bf16)x[2]; r[3] = (__bf16)x[3];
  r[4] = (__bf16)y[0]; r[5] = (__bf16)y[1]; r[6] = (__bf16)y[2]; r[7] = (__bf16)y[3];
  return r;
}

union Smem {
  char gemmBl[2][8192];                       // 16 KB (gemm B tile, dbuf, swizzled)
  struct {
    u16 Plds[8][16][36];                      // 9216 B
    float Osh[8][16][68];                     // 34816 B
    float msh[8][16];
    float lsh[8][16];                         // 1024 B
  } fl;                                       // 45056 B
  float ttile[64][65];                        // 16640 B
  float red[8];
};

struct MegaArgs {
  const float *hs, *rc, *rs, *pk, *pv, *qkvw, *ow, *guw, *dw, *nw;
  float* out;
  char* ws;
  int* bar;
};

// ---------- grid barrier (all 256 blocks co-resident via cooperative launch)
__device__ __forceinline__ void gsync(int* bar, int ph) {
  __syncthreads();
  if (threadIdx.x == 0) {
    __threadfence();
    __hip_atomic_fetch_add(&bar[ph], 1, __ATOMIC_RELEASE, __HIP_MEMORY_SCOPE_AGENT);
    while (__hip_atomic_load(&bar[ph], __ATOMIC_ACQUIRE, __HIP_MEMORY_SCOPE_AGENT) < (int)gridDim.x)
      __builtin_amdgcn_s_sleep(8);
    __threadfence();
  }
  __syncthreads();
}

// ---------- gemm core: acc[2x2] (32Mx32N per wave-row-group) over NBK*128 k
// abase: A bf16 row (w*32+r0), already offset by kb + g*8. bsrc: per-thread fp32 B
// pointer (row trow of the 32-row B tile), already offset kb + tcol*8. K = row stride.
template<int NBK>
__device__ __forceinline__ void gemm_core(const u16* abase, const float* bsrc,
                                          int K, Smem& sm, f32x4 acc[2][2]) {
  int tid = threadIdx.x, lane = tid & 63;
  int r0 = lane & 15, g = lane >> 4;
  int trow = tid >> 4, tcol = tid & 15;
  int swr = (trow & 7) << 4;
  int wofs = trow * 256 + ((tcol * 16) ^ swr);

  {
    f32x4 u = *(const f32x4*)bsrc;
    f32x4 v = *(const f32x4*)(bsrc + 4);
    *(bf16x8*)&sm.gemmBl[0][wofs] = cvt2(u, v);
  }
  bf16x8 a[2][2][4];
#pragma unroll
  for (int mi = 0; mi < 2; mi++)
#pragma unroll
    for (int kk = 0; kk < 4; kk++)
      a[0][mi][kk] = *(const bf16x8*)(abase + (long long)mi * 16 * K + kk * 32);

#pragma unroll
  for (int i = 0; i < 2; i++)
#pragma unroll
    for (int j = 0; j < 2; j++) acc[i][j] = (f32x4){0.f, 0.f, 0.f, 0.f};

  __syncthreads();

#pragma unroll
  for (int ibk = 0; ibk < NBK; ibk++) {
    const int cur = ibk & 1;
    const int nxt = cur ^ 1;
    f32x4 u, v;
    if (ibk + 1 < NBK) {
      int ko = (ibk + 1) * 128;
#pragma unroll
      for (int mi = 0; mi < 2; mi++)
#pragma unroll
        for (int kk = 0; kk < 4; kk++)
          a[nxt][mi][kk] = *(const bf16x8*)(abase + (long long)mi * 16 * K + ko + kk * 32);
      u = *(const f32x4*)(bsrc + ko);
      v = *(const f32x4*)(bsrc + ko + 4);
    }
    bf16x8 bfr[2][4];
#pragma unroll
    for (int nj = 0; nj < 2; nj++) {
      int row = nj * 16 + r0;
      int rb = row * 256, sw = (row & 7) << 4;
#pragma unroll
      for (int kk = 0; kk < 4; kk++)
        bfr[nj][kk] = *(const bf16x8*)&sm.gemmBl[cur][rb + ((kk * 64 + g * 16) ^ sw)];
    }
#pragma unroll
    for (int kk = 0; kk < 4; kk++)
#pragma unroll
      for (int mi = 0; mi < 2; mi++)
#pragma unroll
        for (int nj = 0; nj < 2; nj++)
          acc[mi][nj] = __builtin_amdgcn_mfma_f32_16x16x32_bf16(a[cur][mi][kk], bfr[nj][kk], acc[mi][nj], 0, 0, 0);
    if (ibk + 1 < NBK)
      *(bf16x8*)&sm.gemmBl[nxt][wofs] = cvt2(u, v);
    __syncthreads();
  }
}

// ---------- rms phase: h = src + sum(parts); x = bf16(h * rsqrt(sum h^2))
__device__ void phase_rms(const float* src, const float* parts, int np,
                          float* hout, u16* xout, Smem& sm) {
  int s = blockIdx.x, tid = threadIdx.x, lane = tid & 63, w = tid >> 6;
  f32x4 hv = (f32x4){0.f, 0.f, 0.f, 0.f};
  if (tid < 256) {
    hv = ((const f32x4*)(src + s * 1024))[tid];
    for (int p = 0; p < np; p++) {
      f32x4 pv = ((const f32x4*)(parts + (long long)p * 262144 + s * 1024))[tid];
      hv[0] += pv[0]; hv[1] += pv[1]; hv[2] += pv[2]; hv[3] += pv[3];
    }
  }
  float ss = hv[0]*hv[0] + hv[1]*hv[1] + hv[2]*hv[2] + hv[3]*hv[3];
#pragma unroll
  for (int off = 32; off > 0; off >>= 1) ss += __shfl_xor(ss, off, 64);
  if (lane == 0) sm.red[w] = ss;
  __syncthreads();
  ss = sm.red[0] + sm.red[1] + sm.red[2] + sm.red[3];
  float r = 1.0f / sqrtf(ss);
  if (tid < 256) {
    ((f32x4*)(hout + s * 1024))[tid] = hv;
    u16x4 o;
#pragma unroll
    for (int c = 0; c < 4; c++) o[c] = f2bf(hv[c] * r);
    ((u16x4*)xout)[s * 256 + tid] = o;
  }
}

// ---------- final phase
__device__ void phase_final(const float* src, const float* parts,
                            const float* nw, float* out, Smem& sm) {
  int s = blockIdx.x, tid = threadIdx.x, lane = tid & 63, w = tid >> 6;
  f32x4 hv = (f32x4){0.f, 0.f, 0.f, 0.f};
  if (tid < 256) {
    hv = ((const f32x4*)(src + s * 1024))[tid];
    for (int p = 0; p < 8; p++) {
      f32x4 pv = ((const f32x4*)(parts + (long long)p * 262144 + s * 1024))[tid];
      hv[0] += pv[0]; hv[1] += pv[1]; hv[2] += pv[2]; hv[3] += pv[3];
    }
  }
  float ss = hv[0]*hv[0] + hv[1]*hv[1] + hv[2]*hv[2] + hv[3]*hv[3];
#pragma unroll
  for (int off = 32; off > 0; off >>= 1) ss += __shfl_xor(ss, off, 64);
  if (lane == 0) sm.red[w] = ss;
  __syncthreads();
  ss = sm.red[0] + sm.red[1] + sm.red[2] + sm.red[3];
  float r = 1.0f / sqrtf(ss * (1.0f / 1024.0f) + 1e-6f);
  if (tid < 256) {
    f32x4 wv = ((const f32x4*)nw)[tid];
    f32x4 o;
    o[0]=hv[0]*r*wv[0]; o[1]=hv[1]*r*wv[1]; o[2]=hv[2]*r*wv[2]; o[3]=hv[3]*r*wv[3];
    ((f32x4*)(out + s * 1024))[tid] = o;
  }
}

// ---------- transpose one 64x64 tile of past K or V
__device__ void transpose_unit(int unit, const float* pk, const float* pv,
                               u16* Kb, u16* Vb, Smem& sm) {
  int xt = unit & 31, rest = unit >> 5;
  int kvh = rest & 1, z = rest >> 1;
  int l = z >> 1, part = z & 1;
  int lk = l * 2 + kvh;
  int t0 = xt * 64, tid = threadIdx.x;
  if (part == 0) {
    const float* src = pk + (long long)lk * 131072;           // [d][t]
#pragma unroll
    for (int r = 0; r < 8; r++) {
      int idx = r * 512 + tid; int d = idx >> 6, t = idx & 63;
      sm.ttile[d][t] = src[d * 2048 + t0 + t];
    }
    __syncthreads();
    u16* dst = Kb + (long long)lk * 147456;                   // [t][d]
#pragma unroll
    for (int r = 0; r < 8; r++) {
      int idx = r * 512 + tid; int t = idx >> 6, d = idx & 63;
      dst[(t0 + t) * 64 + d] = f2bf(sm.ttile[d][t]);
    }
  } else {
    const float* src = pv + (long long)lk * 131072;           // [t][d]
#pragma unroll
    for (int r = 0; r < 8; r++) {
      int idx = r * 512 + tid; int t = idx >> 6, d = idx & 63;
      sm.ttile[t][d] = src[(t0 + t) * 64 + d];
    }
    __syncthreads();
    u16* dst = Vb + (long long)lk * 147456;                   // [d][t]
#pragma unroll
    for (int r = 0; r < 8; r++) {
      int idx = r * 512 + tid; int d = idx >> 6, t = idx & 63;
      dst[d * 2304 + t0 + t] = f2bf(sm.ttile[t][d]);
    }
  }
  __syncthreads();
}

// ---------- flash attention phase: block = (qt 0..15, hh 0..15); 8 waves x 288 T
struct KV { bf16x8 kf[2][2]; bf16x8 vf[4]; };

__device__ void phase_flash(const u16* qb, const u16* Kb2, const u16* Vb2,
                            u16* oacc, Smem& sm) {
  int bid = blockIdx.x, tid = threadIdx.x, lane = tid & 63, w = tid >> 6;
  int g = lane >> 4, r0 = lane & 15;
  int hh = bid & 15, qt = bid >> 4;
  int s0 = qt * 16, kvh = hh >> 3;

  const u16* Q  = qb  + hh * 16384;
  const u16* Kh = Kb2 + kvh * 147456;
  const u16* Vh = Vb2 + kvh * 147456;

  bf16x8 qf[2];
#pragma unroll
  for (int kk = 0; kk < 2; kk++)
    qf[kk] = *(const bf16x8*)(Q + (s0 + r0) * 64 + kk * 32 + g * 8);

  f32x4 O[4];
#pragma unroll
  for (int dj = 0; dj < 4; dj++) O[dj] = (f32x4){0.f, 0.f, 0.f, 0.f};
  float m = -1e30f, l = 0.f;

  int t0s = w * 288;

  auto loadkv = [&](KV& d, int t0) {
#pragma unroll
    for (int tj = 0; tj < 2; tj++)
#pragma unroll
      for (int kk = 0; kk < 2; kk++)
        d.kf[tj][kk] = *(const bf16x8*)(Kh + (t0 + tj * 16 + r0) * 64 + kk * 32 + g * 8);
#pragma unroll
    for (int dj = 0; dj < 4; dj++)
      d.vf[dj] = *(const bf16x8*)(Vh + (dj * 16 + r0) * 2304 + t0 + g * 8);
  };

  auto step = [&](KV& kv, int t0) {
    f32x4 sc[2];
#pragma unroll
    for (int tj = 0; tj < 2; tj++) {
      f32x4 z = (f32x4){0.f, 0.f, 0.f, 0.f};
      z = __builtin_amdgcn_mfma_f32_16x16x32_bf16(kv.kf[tj][0], qf[0], z, 0, 0, 0);
      z = __builtin_amdgcn_mfma_f32_16x16x32_bf16(kv.kf[tj][1], qf[1], z, 0, 0, 0);
      sc[tj] = z;
    }
    if (t0 + 31 > 2048 + s0) {
#pragma unroll
      for (int tj = 0; tj < 2; tj++)
#pragma unroll
        for (int q = 0; q < 4; q++) {
          int tg = t0 + tj * 16 + g * 4 + q;
          int sg = s0 + r0;
          if (tg > 2048 + sg) sc[tj][q] = -1e30f;
        }
    }
    float rm = -1e30f;
#pragma unroll
    for (int tj = 0; tj < 2; tj++)
#pragma unroll
      for (int q = 0; q < 4; q++) rm = fmaxf(rm, sc[tj][q]);
    rm = fmaxf(rm, __shfl_xor(rm, 16, 64));
    rm = fmaxf(rm, __shfl_xor(rm, 32, 64));
    float mn = fmaxf(m, rm);
    float sca = __expf(m - mn);
    float rs = 0.f;
#pragma unroll
    for (int tj = 0; tj < 2; tj++)
#pragma unroll
      for (int q = 0; q < 4; q++) {
        sc[tj][q] = __expf(sc[tj][q] - mn);
        rs += sc[tj][q];
      }
    rs += __shfl_xor(rs, 16, 64);
    rs += __shfl_xor(rs, 32, 64);
    l = l * sca + rs;
    m = mn;
#pragma unroll
    for (int dj = 0; dj < 4; dj++) {
      O[dj][0] *= sca; O[dj][1] *= sca; O[dj][2] *= sca; O[dj][3] *= sca;
    }
#pragma unroll
    for (int tj = 0; tj < 2; tj++) {
      u16x4 pw;
#pragma unroll
      for (int q = 0; q < 4; q++) pw[q] = f2bf(sc[tj][q]);
      *(u16x4*)&sm.fl.Plds[w][r0][tj * 16 + g * 4] = pw;
    }
    u16x4 plo = *(const u16x4*)&sm.fl.Plds[w][r0][g * 8];
    u16x4 phi = *(const u16x4*)&sm.fl.Plds[w][r0][g * 8 + 4];
    union { bf16x8 v; u16x4 h[2]; } pu;
    pu.h[0] = plo; pu.h[1] = phi;
#pragma unroll
    for (int dj = 0; dj < 4; dj++)
      O[dj] = __builtin_amdgcn_mfma_f32_16x16x32_bf16(kv.vf[dj], pu.v, O[dj], 0, 0, 0);
  };

  KV ba, bb;
  loadkv(ba, t0s);
#pragma unroll 1
  for (int p = 0; p < 4; p++) {
    int t0 = t0s + p * 64;
    loadkv(bb, t0 + 32);
    step(ba, t0);
    loadkv(ba, t0 + 64);
    step(bb, t0 + 32);
  }
  step(ba, t0s + 256);

#pragma unroll
  for (int dj = 0; dj < 4; dj++)
    *(f32x4*)&sm.fl.Osh[w][r0][dj * 16 + g * 4] = O[dj];
  if (g == 0) { sm.fl.msh[w][r0] = m; sm.fl.lsh[w][r0] = l; }
  __syncthreads();

  if (tid < 256) {
    int row = tid >> 4, c0 = (tid & 15) * 4;
    float M = -1e30f;
#pragma unroll
    for (int w8 = 0; w8 < 8; w8++) M = fmaxf(M, sm.fl.msh[w8][row]);
    float L = 0.f;
    float a0 = 0.f, a1 = 0.f, a2 = 0.f, a3 = 0.f;
#pragma unroll
    for (int w8 = 0; w8 < 8; w8++) {
      float e = __expf(sm.fl.msh[w8][row] - M);
      L += sm.fl.lsh[w8][row] * e;
      f32x4 ov = *(const f32x4*)&sm.fl.Osh[w8][row][c0];
      a0 += e * ov[0]; a1 += e * ov[1]; a2 += e * ov[2]; a3 += e * ov[3];
    }
    float inv = 1.0f / L;
    u16x4 o4;
    o4[0] = f2bf(a0 * inv); o4[1] = f2bf(a1 * inv);
    o4[2] = f2bf(a2 * inv); o4[3] = f2bf(a3 * inv);
    *(u16x4*)(oacc + (long long)(s0 + row) * 1024 + hh * 64 + c0) = o4;
  }
}

// ---------- the megakernel ----------
__global__ __launch_bounds__(512, 2) void mega(MegaArgs A) {
  __shared__ Smem sm;
  int* bar = A.bar;
  int ph = 0;
  const int bid = blockIdx.x, tid = threadIdx.x;
  const int lane = tid & 63, w = tid >> 6;
  const int r0 = lane & 15, g = lane >> 4;
  const int trow = tid >> 4, tcol = tid & 15;
  const int rr = (lane >> 4) << 2;

  char* ws = A.ws;
  float* h    = (float*)(ws);
  u16*   x    = (u16*)(ws + 1048576);
  float* Pq   = (float*)(ws + 1572864);       // 4 x [256][1280]
  float* Po   = (float*)(ws + 6815744);       // 8 x [256][1024]
  float* Pd   = (float*)(ws + 15204352);      // 8 x [256][1024]
  u16*   y    = (u16*)(ws + 23592960);        // [256][4096]
  u16*   oacc = (u16*)(ws + 25690112);        // [256][1024]
  u16*   qb   = (u16*)(ws + 26214400);        // [16][256][64]
  u16*   Kb   = (u16*)(ws + 26738688);        // [8][2][2304][64]
  u16*   Vb   = (u16*)(ws + 31457280);        // [8][2][64][2304]

  // phase T: transpose all past K/V (1024 tiles / 256 blocks)
  for (int u = 0; u < 4; u++)
    transpose_unit(bid * 4 + u, A.pk, A.pv, Kb, Vb, sm);
  gsync(bar, ph++);

  for (int l = 0; l < 8; l++) {
    const float* qkvw_l = A.qkvw + (long long)l * 1310720;
    const float* ow_l   = A.ow   + (long long)l * 1048576;
    const float* guw_l  = A.guw  + (long long)l * 8388608;
    const float* dw_l   = A.dw   + (long long)l * 4194304;
    u16* Kbl = Kb + (long long)l * 294912;
    u16* Vbl = Vb + (long long)l * 294912;

    // P0: residual(+down partials) + rmsnorm
    phase_rms(l == 0 ? A.hs : h, Pd, l == 0 ? 0 : 8, h, x, sm);
    gsync(bar, ph++);

    // P1: qkv GEMM, 40 n-tiles x 4 ksplit = 160 units
    if (bid < 160) {
      int nt = bid % 40, slab = bid / 40;
      int n0 = nt * 32, kb = slab * 256;
      const u16* abase = x + (long long)(w * 32 + r0) * 1024 + g * 8 + kb;
      const float* bsrc = qkvw_l + (long long)(n0 + trow) * 1024 + kb + tcol * 8;
      f32x4 acc[2][2];
      gemm_core<2>(abase, bsrc, 1024, sm, acc);
      float* dst = Pq + (long long)slab * 327680;
#pragma unroll
      for (int mi = 0; mi < 2; mi++)
#pragma unroll
        for (int nj = 0; nj < 2; nj++)
#pragma unroll
          for (int q = 0; q < 4; q++) {
            int row = w * 32 + mi * 16 + rr + q;
            dst[row * 1280 + n0 + nj * 16 + r0] = acc[mi][nj][q];
          }
    }
    gsync(bar, ph++);

    // P2: rope + scatter (sums 4 qkv partials)
    {
      int s = bid;
      for (int i = tid; i < 1280; i += 512) {
        int hh = i >> 6, d = i & 63;
        long long o0 = (long long)s * 1280;
        float v = Pq[o0 + i] + Pq[327680 + o0 + i] + Pq[655360 + o0 + i] + Pq[983040 + o0 + i];
        if (hh < 18) {
          int j = (hh << 6) | ((d + 32) & 63);
          float vr = Pq[o0 + j] + Pq[327680 + o0 + j] + Pq[655360 + o0 + j] + Pq[983040 + o0 + j];
          v = v * A.rc[s * 64 + d] + vr * A.rs[s * 64 + d];
          if (hh < 16) qb[hh * 16384 + s * 64 + d] = f2bf(v);
          else         Kbl[(hh - 16) * 147456 + (2048 + s) * 64 + d] = f2bf(v);
        } else {
          Vbl[(hh - 18) * 147456 + d * 2304 + 2048 + s] = f2bf(v);
        }
      }
    }
    gsync(bar, ph++);

    // P3: flash attention (256 units exactly)
    phase_flash(qb, Kbl, Vbl, oacc, sm);
    gsync(bar, ph++);

    // P4: o-proj GEMM, 32 n-tiles x 8 ksplit = 256 units
    {
      int n_idx = bid & 31, slab = bid >> 5;
      int n0 = n_idx * 32, kb = slab * 128;
      const u16* abase = oacc + (long long)(w * 32 + r0) * 1024 + g * 8 + kb;
      const float* bsrc = ow_l + (long long)(n0 + trow) * 1024 + kb + tcol * 8;
      f32x4 acc[2][2];
      gemm_core<1>(abase, bsrc, 1024, sm, acc);
      float* dst = Po + (long long)slab * 262144;
#pragma unroll
      for (int mi = 0; mi < 2; mi++)
#pragma unroll
        for (int nj = 0; nj < 2; nj++)
#pragma unroll
          for (int q = 0; q < 4; q++) {
            int row = w * 32 + mi * 16 + rr + q;
            dst[row * 1024 + n0 + nj * 16 + r0] = acc[mi][nj][q];
          }
    }
    gsync(bar, ph++);

    // P5: residual(o partials) + rmsnorm
    phase_rms(h, Po, 8, h, x, sm);
    gsync(bar, ph++);

    // P6: gate_up GEMM + fused silu*up -> y ; unit = 16-col pair, 256 units
    {
      int n0 = bid * 16;
      const u16* abase = x + (long long)(w * 32 + r0) * 1024 + g * 8;
      const float* brow = (trow < 16)
          ? (guw_l + (long long)(n0 + trow) * 1024)
          : (guw_l + (long long)(4096 + n0 + trow - 16) * 1024);
      const float* bsrc = brow + tcol * 8;
      f32x4 acc[2][2];
      gemm_core<8>(abase, bsrc, 1024, sm, acc);
#pragma unroll
      for (int mi = 0; mi < 2; mi++)
#pragma unroll
        for (int q = 0; q < 4; q++) {
          int row = w * 32 + mi * 16 + rr + q;
          float gv = acc[mi][0][q], uv = acc[mi][1][q];
          y[(long long)row * 4096 + n0 + r0] = f2bf((gv / (1.0f + __expf(-gv))) * uv);
        }
    }
    gsync(bar, ph++);

    // P7: down GEMM, 32 n-tiles x 8 ksplit = 256 units
    {
      int n_idx = bid & 31, slab = bid >> 5;
      int n0 = n_idx * 32, kb = slab * 512;
      const u16* abase = y + (long long)(w * 32 + r0) * 4096 + g * 8 + kb;
      const float* bsrc = dw_l + (long long)(n0 + trow) * 4096 + kb + tcol * 8;
      f32x4 acc[2][2];
      gemm_core<4>(abase, bsrc, 4096, sm, acc);
      float* dst = Pd + (long long)slab * 262144;
#pragma unroll
      for (int mi = 0; mi < 2; mi++)
#pragma unroll
        for (int nj = 0; nj < 2; nj++)
#pragma unroll
          for (int q = 0; q < 4; q++) {
            int row = w * 32 + mi * 16 + rr + q;
            dst[row * 1024 + n0 + nj * 16 + r0] = acc[mi][nj][q];
          }
    }
    gsync(bar, ph++);
  }

  phase_final(h, Pd, A.nw, A.out, sm);
}

// ---------------- launch ----------------
extern "C" void kernel_launch(void* const* d_in, const int* in_sizes, int n_in,
                              void* d_out, int out_size, void* d_ws, size_t ws_size,
                              hipStream_t stream) {
  (void)in_sizes; (void)n_in; (void)out_size; (void)ws_size;
  MegaArgs ma;
  ma.hs   = (const float*)d_in[0];
  ma.rc   = (const float*)d_in[1];
  ma.rs   = (const float*)d_in[2];
  ma.pk   = (const float*)d_in[4];
  ma.pv   = (const float*)d_in[5];
  ma.qkvw = (const float*)d_in[6];
  ma.ow   = (const float*)d_in[7];
  ma.guw  = (const float*)d_in[8];
  ma.dw   = (const float*)d_in[9];
  ma.nw   = (const float*)d_in[10];
  ma.out  = (float*)d_out;
  ma.ws   = (char*)d_ws;
  ma.bar  = (int*)((char*)d_ws + 36175872);

  hipMemsetAsync((char*)d_ws + 36175872, 0, 1024, stream);
  void* kargs[] = { (void*)&ma };
  hipLaunchCooperativeKernel((const void*)mega, dim3(256), dim3(512), kargs, 0, stream);
}

// Round 6
// 1693.291 us; speedup vs baseline: 1.6054x; 1.6054x over previous
//
#include <hip/hip_runtime.h>
#include <hip/hip_bf16.h>

typedef __attribute__((ext_vector_type(4))) float f32x4;
typedef __attribute__((ext_vector_type(8))) __bf16 bf16x8;
typedef unsigned short u16;
typedef __attribute__((ext_vector_type(4))) unsigned short u16x4;

__device__ __forceinline__ u16 f2bf(float f) {
  __bf16 h = (__bf16)f;
  return __builtin_bit_cast(u16, h);
}

__device__ __forceinline__ bf16x8 cvt2(f32x4 x, f32x4 y) {
  bf16x8 r;
  r[0] = (__bf16)x[0]; r[1] = (__bf16)x[1]; r[2] = (__bf16)x[2]; r[3] = (__bf16)x[3];
  r[4] = (__bf16)y[0]; r[5] = (__bf16)y[1]; r[6] = (__bf16)y[2]; r[7] = (__bf16)y[3];
  return r;
}

union Smem {
  char gemmBl[2][8192];                       // 16 KB (gemm B tile, dbuf, swizzled)
  struct {
    u16 Plds[8][16][36];                      // 9216 B
    float Osh[8][16][68];                     // 34816 B
    float msh[8][16];
    float lsh[8][16];                         // 1024 B
  } fl;                                       // 45056 B
  float ttile[64][65];                        // 16640 B
  float red[8];
};

struct MegaArgs {
  const float *hs, *rc, *rs, *pk, *pv, *qkvw, *ow, *guw, *dw, *nw;
  float* out;
  char* ws;
  int* bar;
};

// ---------- grid barrier (256 co-resident blocks, cooperative launch)
// arrive: RELEASE fetch_add (one L2 writeback). spin: RELAXED atomic loads —
// they go to the coherence point but do NO cache maintenance (the round-5
// version did an acquire per poll -> per-XCD L2 invalidate storm, 4x slowdown).
// exit: ONE acquire fence (one L1/L2 invalidate), then block-barrier.
__device__ __forceinline__ void gsync(int* bar, int ph) {
  __syncthreads();
  if (threadIdx.x == 0) {
    __hip_atomic_fetch_add(&bar[ph], 1, __ATOMIC_RELEASE, __HIP_MEMORY_SCOPE_AGENT);
    while (__hip_atomic_load(&bar[ph], __ATOMIC_RELAXED, __HIP_MEMORY_SCOPE_AGENT) < (int)gridDim.x)
      __builtin_amdgcn_s_sleep(16);
    __builtin_amdgcn_fence(__ATOMIC_ACQUIRE, "agent");
  }
  __syncthreads();
}

// ---------- gemm core: acc[2x2] (32Mx32N per wave-row-group) over NBK*128 k
template<int NBK>
__device__ __forceinline__ void gemm_core(const u16* abase, const float* bsrc,
                                          int K, Smem& sm, f32x4 acc[2][2]) {
  int tid = threadIdx.x, lane = tid & 63;
  int r0 = lane & 15, g = lane >> 4;
  int trow = tid >> 4, tcol = tid & 15;
  int swr = (trow & 7) << 4;
  int wofs = trow * 256 + ((tcol * 16) ^ swr);

  {
    f32x4 u = *(const f32x4*)bsrc;
    f32x4 v = *(const f32x4*)(bsrc + 4);
    *(bf16x8*)&sm.gemmBl[0][wofs] = cvt2(u, v);
  }
  bf16x8 a[2][2][4];
#pragma unroll
  for (int mi = 0; mi < 2; mi++)
#pragma unroll
    for (int kk = 0; kk < 4; kk++)
      a[0][mi][kk] = *(const bf16x8*)(abase + (long long)mi * 16 * K + kk * 32);

#pragma unroll
  for (int i = 0; i < 2; i++)
#pragma unroll
    for (int j = 0; j < 2; j++) acc[i][j] = (f32x4){0.f, 0.f, 0.f, 0.f};

  __syncthreads();

#pragma unroll
  for (int ibk = 0; ibk < NBK; ibk++) {
    const int cur = ibk & 1;
    const int nxt = cur ^ 1;
    f32x4 u, v;
    if (ibk + 1 < NBK) {
      int ko = (ibk + 1) * 128;
#pragma unroll
      for (int mi = 0; mi < 2; mi++)
#pragma unroll
        for (int kk = 0; kk < 4; kk++)
          a[nxt][mi][kk] = *(const bf16x8*)(abase + (long long)mi * 16 * K + ko + kk * 32);
      u = *(const f32x4*)(bsrc + ko);
      v = *(const f32x4*)(bsrc + ko + 4);
    }
    bf16x8 bfr[2][4];
#pragma unroll
    for (int nj = 0; nj < 2; nj++) {
      int row = nj * 16 + r0;
      int rb = row * 256, sw = (row & 7) << 4;
#pragma unroll
      for (int kk = 0; kk < 4; kk++)
        bfr[nj][kk] = *(const bf16x8*)&sm.gemmBl[cur][rb + ((kk * 64 + g * 16) ^ sw)];
    }
#pragma unroll
    for (int kk = 0; kk < 4; kk++)
#pragma unroll
      for (int mi = 0; mi < 2; mi++)
#pragma unroll
        for (int nj = 0; nj < 2; nj++)
          acc[mi][nj] = __builtin_amdgcn_mfma_f32_16x16x32_bf16(a[cur][mi][kk], bfr[nj][kk], acc[mi][nj], 0, 0, 0);
    if (ibk + 1 < NBK)
      *(bf16x8*)&sm.gemmBl[nxt][wofs] = cvt2(u, v);
    __syncthreads();
  }
}

// ---------- rms phase: h = src + sum(parts); x = bf16(h * rsqrt(sum h^2))
__device__ void phase_rms(const float* src, const float* parts, int np,
                          float* hout, u16* xout, Smem& sm) {
  int s = blockIdx.x, tid = threadIdx.x, lane = tid & 63, w = tid >> 6;
  f32x4 hv = (f32x4){0.f, 0.f, 0.f, 0.f};
  if (tid < 256) {
    hv = ((const f32x4*)(src + s * 1024))[tid];
    for (int p = 0; p < np; p++) {
      f32x4 pv = ((const f32x4*)(parts + (long long)p * 262144 + s * 1024))[tid];
      hv[0] += pv[0]; hv[1] += pv[1]; hv[2] += pv[2]; hv[3] += pv[3];
    }
  }
  float ss = hv[0]*hv[0] + hv[1]*hv[1] + hv[2]*hv[2] + hv[3]*hv[3];
#pragma unroll
  for (int off = 32; off > 0; off >>= 1) ss += __shfl_xor(ss, off, 64);
  if (lane == 0) sm.red[w] = ss;
  __syncthreads();
  ss = sm.red[0] + sm.red[1] + sm.red[2] + sm.red[3];
  float r = 1.0f / sqrtf(ss);
  if (tid < 256) {
    ((f32x4*)(hout + s * 1024))[tid] = hv;
    u16x4 o;
#pragma unroll
    for (int c = 0; c < 4; c++) o[c] = f2bf(hv[c] * r);
    ((u16x4*)xout)[s * 256 + tid] = o;
  }
}

// ---------- final phase
__device__ void phase_final(const float* src, const float* parts,
                            const float* nw, float* out, Smem& sm) {
  int s = blockIdx.x, tid = threadIdx.x, lane = tid & 63, w = tid >> 6;
  f32x4 hv = (f32x4){0.f, 0.f, 0.f, 0.f};
  if (tid < 256) {
    hv = ((const f32x4*)(src + s * 1024))[tid];
    for (int p = 0; p < 8; p++) {
      f32x4 pv = ((const f32x4*)(parts + (long long)p * 262144 + s * 1024))[tid];
      hv[0] += pv[0]; hv[1] += pv[1]; hv[2] += pv[2]; hv[3] += pv[3];
    }
  }
  float ss = hv[0]*hv[0] + hv[1]*hv[1] + hv[2]*hv[2] + hv[3]*hv[3];
#pragma unroll
  for (int off = 32; off > 0; off >>= 1) ss += __shfl_xor(ss, off, 64);
  if (lane == 0) sm.red[w] = ss;
  __syncthreads();
  ss = sm.red[0] + sm.red[1] + sm.red[2] + sm.red[3];
  float r = 1.0f / sqrtf(ss * (1.0f / 1024.0f) + 1e-6f);
  if (tid < 256) {
    f32x4 wv = ((const f32x4*)nw)[tid];
    f32x4 o;
    o[0]=hv[0]*r*wv[0]; o[1]=hv[1]*r*wv[1]; o[2]=hv[2]*r*wv[2]; o[3]=hv[3]*r*wv[3];
    ((f32x4*)(out + s * 1024))[tid] = o;
  }
}

// ---------- transpose one 64x64 tile of past K or V
__device__ void transpose_unit(int unit, const float* pk, const float* pv,
                               u16* Kb, u16* Vb, Smem& sm) {
  int xt = unit & 31, rest = unit >> 5;
  int kvh = rest & 1, z = rest >> 1;
  int l = z >> 1, part = z & 1;
  int lk = l * 2 + kvh;
  int t0 = xt * 64, tid = threadIdx.x;
  if (part == 0) {
    const float* src = pk + (long long)lk * 131072;           // [d][t]
#pragma unroll
    for (int r = 0; r < 8; r++) {
      int idx = r * 512 + tid; int d = idx >> 6, t = idx & 63;
      sm.ttile[d][t] = src[d * 2048 + t0 + t];
    }
    __syncthreads();
    u16* dst = Kb + (long long)lk * 147456;                   // [t][d]
#pragma unroll
    for (int r = 0; r < 8; r++) {
      int idx = r * 512 + tid; int t = idx >> 6, d = idx & 63;
      dst[(t0 + t) * 64 + d] = f2bf(sm.ttile[d][t]);
    }
  } else {
    const float* src = pv + (long long)lk * 131072;           // [t][d]
#pragma unroll
    for (int r = 0; r < 8; r++) {
      int idx = r * 512 + tid; int t = idx >> 6, d = idx & 63;
      sm.ttile[t][d] = src[(t0 + t) * 64 + d];
    }
    __syncthreads();
    u16* dst = Vb + (long long)lk * 147456;                   // [d][t]
#pragma unroll
    for (int r = 0; r < 8; r++) {
      int idx = r * 512 + tid; int d = idx >> 6, t = idx & 63;
      dst[d * 2304 + t0 + t] = f2bf(sm.ttile[t][d]);
    }
  }
  __syncthreads();
}

// ---------- flash attention phase: block = (qt 0..15, hh 0..15); 8 waves x 288 T
struct KV { bf16x8 kf[2][2]; bf16x8 vf[4]; };

__device__ void phase_flash(const u16* qb, const u16* Kb2, const u16* Vb2,
                            u16* oacc, Smem& sm) {
  int bid = blockIdx.x, tid = threadIdx.x, lane = tid & 63, w = tid >> 6;
  int g = lane >> 4, r0 = lane & 15;
  int hh = bid & 15, qt = bid >> 4;
  int s0 = qt * 16, kvh = hh >> 3;

  const u16* Q  = qb  + hh * 16384;
  const u16* Kh = Kb2 + kvh * 147456;
  const u16* Vh = Vb2 + kvh * 147456;

  bf16x8 qf[2];
#pragma unroll
  for (int kk = 0; kk < 2; kk++)
    qf[kk] = *(const bf16x8*)(Q + (s0 + r0) * 64 + kk * 32 + g * 8);

  f32x4 O[4];
#pragma unroll
  for (int dj = 0; dj < 4; dj++) O[dj] = (f32x4){0.f, 0.f, 0.f, 0.f};
  float m = -1e30f, l = 0.f;

  int t0s = w * 288;

  auto loadkv = [&](KV& d, int t0) {
#pragma unroll
    for (int tj = 0; tj < 2; tj++)
#pragma unroll
      for (int kk = 0; kk < 2; kk++)
        d.kf[tj][kk] = *(const bf16x8*)(Kh + (t0 + tj * 16 + r0) * 64 + kk * 32 + g * 8);
#pragma unroll
    for (int dj = 0; dj < 4; dj++)
      d.vf[dj] = *(const bf16x8*)(Vh + (dj * 16 + r0) * 2304 + t0 + g * 8);
  };

  auto step = [&](KV& kv, int t0) {
    f32x4 sc[2];
#pragma unroll
    for (int tj = 0; tj < 2; tj++) {
      f32x4 z = (f32x4){0.f, 0.f, 0.f, 0.f};
      z = __builtin_amdgcn_mfma_f32_16x16x32_bf16(kv.kf[tj][0], qf[0], z, 0, 0, 0);
      z = __builtin_amdgcn_mfma_f32_16x16x32_bf16(kv.kf[tj][1], qf[1], z, 0, 0, 0);
      sc[tj] = z;
    }
    if (t0 + 31 > 2048 + s0) {
#pragma unroll
      for (int tj = 0; tj < 2; tj++)
#pragma unroll
        for (int q = 0; q < 4; q++) {
          int tg = t0 + tj * 16 + g * 4 + q;
          int sg = s0 + r0;
          if (tg > 2048 + sg) sc[tj][q] = -1e30f;
        }
    }
    float rm = -1e30f;
#pragma unroll
    for (int tj = 0; tj < 2; tj++)
#pragma unroll
      for (int q = 0; q < 4; q++) rm = fmaxf(rm, sc[tj][q]);
    rm = fmaxf(rm, __shfl_xor(rm, 16, 64));
    rm = fmaxf(rm, __shfl_xor(rm, 32, 64));
    float mn = fmaxf(m, rm);
    float sca = __expf(m - mn);
    float rs = 0.f;
#pragma unroll
    for (int tj = 0; tj < 2; tj++)
#pragma unroll
      for (int q = 0; q < 4; q++) {
        sc[tj][q] = __expf(sc[tj][q] - mn);
        rs += sc[tj][q];
      }
    rs += __shfl_xor(rs, 16, 64);
    rs += __shfl_xor(rs, 32, 64);
    l = l * sca + rs;
    m = mn;
#pragma unroll
    for (int dj = 0; dj < 4; dj++) {
      O[dj][0] *= sca; O[dj][1] *= sca; O[dj][2] *= sca; O[dj][3] *= sca;
    }
#pragma unroll
    for (int tj = 0; tj < 2; tj++) {
      u16x4 pw;
#pragma unroll
      for (int q = 0; q < 4; q++) pw[q] = f2bf(sc[tj][q]);
      *(u16x4*)&sm.fl.Plds[w][r0][tj * 16 + g * 4] = pw;
    }
    u16x4 plo = *(const u16x4*)&sm.fl.Plds[w][r0][g * 8];
    u16x4 phi = *(const u16x4*)&sm.fl.Plds[w][r0][g * 8 + 4];
    union { bf16x8 v; u16x4 h[2]; } pu;
    pu.h[0] = plo; pu.h[1] = phi;
#pragma unroll
    for (int dj = 0; dj < 4; dj++)
      O[dj] = __builtin_amdgcn_mfma_f32_16x16x32_bf16(kv.vf[dj], pu.v, O[dj], 0, 0, 0);
  };

  KV ba, bb;
  loadkv(ba, t0s);
#pragma unroll 1
  for (int p = 0; p < 4; p++) {
    int t0 = t0s + p * 64;
    loadkv(bb, t0 + 32);
    step(ba, t0);
    loadkv(ba, t0 + 64);
    step(bb, t0 + 32);
  }
  step(ba, t0s + 256);

#pragma unroll
  for (int dj = 0; dj < 4; dj++)
    *(f32x4*)&sm.fl.Osh[w][r0][dj * 16 + g * 4] = O[dj];
  if (g == 0) { sm.fl.msh[w][r0] = m; sm.fl.lsh[w][r0] = l; }
  __syncthreads();

  if (tid < 256) {
    int row = tid >> 4, c0 = (tid & 15) * 4;
    float M = -1e30f;
#pragma unroll
    for (int w8 = 0; w8 < 8; w8++) M = fmaxf(M, sm.fl.msh[w8][row]);
    float L = 0.f;
    float a0 = 0.f, a1 = 0.f, a2 = 0.f, a3 = 0.f;
#pragma unroll
    for (int w8 = 0; w8 < 8; w8++) {
      float e = __expf(sm.fl.msh[w8][row] - M);
      L += sm.fl.lsh[w8][row] * e;
      f32x4 ov = *(const f32x4*)&sm.fl.Osh[w8][row][c0];
      a0 += e * ov[0]; a1 += e * ov[1]; a2 += e * ov[2]; a3 += e * ov[3];
    }
    float inv = 1.0f / L;
    u16x4 o4;
    o4[0] = f2bf(a0 * inv); o4[1] = f2bf(a1 * inv);
    o4[2] = f2bf(a2 * inv); o4[3] = f2bf(a3 * inv);
    *(u16x4*)(oacc + (long long)(s0 + row) * 1024 + hh * 64 + c0) = o4;
  }
}

// ---------- the megakernel ----------
__global__ __launch_bounds__(512, 2) void mega(MegaArgs A) {
  __shared__ Smem sm;
  int* bar = A.bar;
  int ph = 0;
  const int bid = blockIdx.x, tid = threadIdx.x;
  const int lane = tid & 63, w = tid >> 6;
  const int r0 = lane & 15, g = lane >> 4;
  const int trow = tid >> 4, tcol = tid & 15;
  const int rr = (lane >> 4) << 2;

  char* ws = A.ws;
  float* h    = (float*)(ws);
  u16*   x    = (u16*)(ws + 1048576);
  float* Pq   = (float*)(ws + 1572864);       // 4 x [256][1280]
  float* Po   = (float*)(ws + 6815744);       // 8 x [256][1024]
  float* Pd   = (float*)(ws + 15204352);      // 8 x [256][1024]
  u16*   y    = (u16*)(ws + 23592960);        // [256][4096]
  u16*   oacc = (u16*)(ws + 25690112);        // [256][1024]
  u16*   qb   = (u16*)(ws + 26214400);        // [16][256][64]
  u16*   Kb   = (u16*)(ws + 26738688);        // [8][2][2304][64]
  u16*   Vb   = (u16*)(ws + 31457280);        // [8][2][64][2304]

  // phase T: transpose all past K/V (1024 tiles / 256 blocks)
  for (int u = 0; u < 4; u++)
    transpose_unit(bid * 4 + u, A.pk, A.pv, Kb, Vb, sm);
  gsync(bar, ph++);

  for (int l = 0; l < 8; l++) {
    const float* qkvw_l = A.qkvw + (long long)l * 1310720;
    const float* ow_l   = A.ow   + (long long)l * 1048576;
    const float* guw_l  = A.guw  + (long long)l * 8388608;
    const float* dw_l   = A.dw   + (long long)l * 4194304;
    u16* Kbl = Kb + (long long)l * 294912;
    u16* Vbl = Vb + (long long)l * 294912;

    // P0: residual(+down partials) + rmsnorm
    phase_rms(l == 0 ? A.hs : h, Pd, l == 0 ? 0 : 8, h, x, sm);
    gsync(bar, ph++);

    // P1: qkv GEMM, 40 n-tiles x 4 ksplit = 160 units
    if (bid < 160) {
      int nt = bid % 40, slab = bid / 40;
      int n0 = nt * 32, kb = slab * 256;
      const u16* abase = x + (long long)(w * 32 + r0) * 1024 + g * 8 + kb;
      const float* bsrc = qkvw_l + (long long)(n0 + trow) * 1024 + kb + tcol * 8;
      f32x4 acc[2][2];
      gemm_core<2>(abase, bsrc, 1024, sm, acc);
      float* dst = Pq + (long long)slab * 327680;
#pragma unroll
      for (int mi = 0; mi < 2; mi++)
#pragma unroll
        for (int nj = 0; nj < 2; nj++)
#pragma unroll
          for (int q = 0; q < 4; q++) {
            int row = w * 32 + mi * 16 + rr + q;
            dst[row * 1280 + n0 + nj * 16 + r0] = acc[mi][nj][q];
          }
    }
    gsync(bar, ph++);

    // P2: rope + scatter (sums 4 qkv partials)
    {
      int s = bid;
      for (int i = tid; i < 1280; i += 512) {
        int hh = i >> 6, d = i & 63;
        long long o0 = (long long)s * 1280;
        float v = Pq[o0 + i] + Pq[327680 + o0 + i] + Pq[655360 + o0 + i] + Pq[983040 + o0 + i];
        if (hh < 18) {
          int j = (hh << 6) | ((d + 32) & 63);
          float vr = Pq[o0 + j] + Pq[327680 + o0 + j] + Pq[655360 + o0 + j] + Pq[983040 + o0 + j];
          v = v * A.rc[s * 64 + d] + vr * A.rs[s * 64 + d];
          if (hh < 16) qb[hh * 16384 + s * 64 + d] = f2bf(v);
          else         Kbl[(hh - 16) * 147456 + (2048 + s) * 64 + d] = f2bf(v);
        } else {
          Vbl[(hh - 18) * 147456 + d * 2304 + 2048 + s] = f2bf(v);
        }
      }
    }
    gsync(bar, ph++);

    // P3: flash attention (256 units exactly)
    phase_flash(qb, Kbl, Vbl, oacc, sm);
    gsync(bar, ph++);

    // P4: o-proj GEMM, 32 n-tiles x 8 ksplit = 256 units
    {
      int n_idx = bid & 31, slab = bid >> 5;
      int n0 = n_idx * 32, kb = slab * 128;
      const u16* abase = oacc + (long long)(w * 32 + r0) * 1024 + g * 8 + kb;
      const float* bsrc = ow_l + (long long)(n0 + trow) * 1024 + kb + tcol * 8;
      f32x4 acc[2][2];
      gemm_core<1>(abase, bsrc, 1024, sm, acc);
      float* dst = Po + (long long)slab * 262144;
#pragma unroll
      for (int mi = 0; mi < 2; mi++)
#pragma unroll
        for (int nj = 0; nj < 2; nj++)
#pragma unroll
          for (int q = 0; q < 4; q++) {
            int row = w * 32 + mi * 16 + rr + q;
            dst[row * 1024 + n0 + nj * 16 + r0] = acc[mi][nj][q];
          }
    }
    gsync(bar, ph++);

    // P5: residual(o partials) + rmsnorm
    phase_rms(h, Po, 8, h, x, sm);
    gsync(bar, ph++);

    // P6: gate_up GEMM + fused silu*up -> y ; unit = 16-col pair, 256 units
    {
      int n0 = bid * 16;
      const u16* abase = x + (long long)(w * 32 + r0) * 1024 + g * 8;
      const float* brow = (trow < 16)
          ? (guw_l + (long long)(n0 + trow) * 1024)
          : (guw_l + (long long)(4096 + n0 + trow - 16) * 1024);
      const float* bsrc = brow + tcol * 8;
      f32x4 acc[2][2];
      gemm_core<8>(abase, bsrc, 1024, sm, acc);
#pragma unroll
      for (int mi = 0; mi < 2; mi++)
#pragma unroll
        for (int q = 0; q < 4; q++) {
          int row = w * 32 + mi * 16 + rr + q;
          float gv = acc[mi][0][q], uv = acc[mi][1][q];
          y[(long long)row * 4096 + n0 + r0] = f2bf((gv / (1.0f + __expf(-gv))) * uv);
        }
    }
    gsync(bar, ph++);

    // P7: down GEMM, 32 n-tiles x 8 ksplit = 256 units
    {
      int n_idx = bid & 31, slab = bid >> 5;
      int n0 = n_idx * 32, kb = slab * 512;
      const u16* abase = y + (long long)(w * 32 + r0) * 4096 + g * 8 + kb;
      const float* bsrc = dw_l + (long long)(n0 + trow) * 4096 + kb + tcol * 8;
      f32x4 acc[2][2];
      gemm_core<4>(abase, bsrc, 4096, sm, acc);
      float* dst = Pd + (long long)slab * 262144;
#pragma unroll
      for (int mi = 0; mi < 2; mi++)
#pragma unroll
        for (int nj = 0; nj < 2; nj++)
#pragma unroll
          for (int q = 0; q < 4; q++) {
            int row = w * 32 + mi * 16 + rr + q;
            dst[row * 1024 + n0 + nj * 16 + r0] = acc[mi][nj][q];
          }
    }
    gsync(bar, ph++);
  }

  phase_final(h, Pd, A.nw, A.out, sm);
}

// ---------------- launch ----------------
extern "C" void kernel_launch(void* const* d_in, const int* in_sizes, int n_in,
                              void* d_out, int out_size, void* d_ws, size_t ws_size,
                              hipStream_t stream) {
  (void)in_sizes; (void)n_in; (void)out_size; (void)ws_size;
  MegaArgs ma;
  ma.hs   = (const float*)d_in[0];
  ma.rc   = (const float*)d_in[1];
  ma.rs   = (const float*)d_in[2];
  ma.pk   = (const float*)d_in[4];
  ma.pv   = (const float*)d_in[5];
  ma.qkvw = (const float*)d_in[6];
  ma.ow   = (const float*)d_in[7];
  ma.guw  = (const float*)d_in[8];
  ma.dw   = (const float*)d_in[9];
  ma.nw   = (const float*)d_in[10];
  ma.out  = (float*)d_out;
  ma.ws   = (char*)d_ws;
  ma.bar  = (int*)((char*)d_ws + 36175872);

  hipMemsetAsync((char*)d_ws + 36175872, 0, 1024, stream);
  void* kargs[] = { (void*)&ma };
  hipLaunchCooperativeKernel((const void*)mega, dim3(256), dim3(512), kargs, 0, stream);
}

// Round 7
// 1581.140 us; speedup vs baseline: 1.7193x; 1.0709x over previous
//
#include <hip/hip_runtime.h>
#include <hip/hip_bf16.h>

typedef __attribute__((ext_vector_type(4))) float f32x4;
typedef __attribute__((ext_vector_type(8))) __bf16 bf16x8;
typedef unsigned short u16;
typedef __attribute__((ext_vector_type(4))) unsigned short u16x4;

__device__ __forceinline__ u16 f2bf(float f) {
  __bf16 h = (__bf16)f;
  return __builtin_bit_cast(u16, h);
}

__device__ __forceinline__ bf16x8 cvt2(f32x4 x, f32x4 y) {
  bf16x8 r;
  r[0] = (__bf16)x[0]; r[1] = (__bf16)x[1]; r[2] = (__bf16)x[2]; r[3] = (__bf16)x[3];
  r[4] = (__bf16)y[0]; r[5] = (__bf16)y[1]; r[6] = (__bf16)y[2]; r[7] = (__bf16)y[3];
  return r;
}

// ---------- write-through (L2-bypass) stores for cross-block intermediates.
// sc0 sc1 => no dirty L2 lines => the barrier's release-wbl2 has nothing to
// flush; readers re-fetch from MALL after the acquire-inv. Loads stay normal
// (cached + compiler-pipelined); acquire-inv at each barrier handles staleness.
__device__ __forceinline__ void stg_wt_f4(float* p, f32x4 v) {
  asm volatile("global_store_dwordx4 %0, %1, off sc0 sc1" :: "v"(p), "v"(v) : "memory");
}
__device__ __forceinline__ void stg_wt_f1(float* p, float v) {
  asm volatile("global_store_dword %0, %1, off sc0 sc1" :: "v"(p), "v"(v) : "memory");
}
__device__ __forceinline__ void stg_wt_u16(u16* p, unsigned v) {
  asm volatile("global_store_short %0, %1, off sc0 sc1" :: "v"(p), "v"(v) : "memory");
}
__device__ __forceinline__ void stg_wt_b8(u16* p, u16x4 v) {
  unsigned long long q = __builtin_bit_cast(unsigned long long, v);
  asm volatile("global_store_dwordx2 %0, %1, off sc0 sc1" :: "v"(p), "v"(q) : "memory");
}

union Smem {
  char gemmBl[2][8192];                       // 16 KB (gemm B tile, dbuf, swizzled)
  struct {
    u16 Plds[8][16][36];                      // 9216 B
    float Osh[8][16][68];                     // 34816 B
    float msh[8][16];
    float lsh[8][16];                         // 1024 B
  } fl;                                       // 45056 B
  float ttile[64][65];                        // 16640 B
  float red[8];
};

struct MegaArgs {
  const float *hs, *rc, *rs, *pk, *pv, *qkvw, *ow, *guw, *dw, *nw;
  float* out;
  char* ws;
  int* bar;
};

// ---------- grid barrier (256 co-resident blocks, cooperative launch)
// arrive: RELEASE fetch_add (wbl2 now ~free: no dirty lines). spin: RELAXED.
// exit: ONE acquire fence (L1/L2 inv), then block-barrier.
__device__ __forceinline__ void gsync(int* bar, int ph) {
  __syncthreads();
  if (threadIdx.x == 0) {
    __hip_atomic_fetch_add(&bar[ph], 1, __ATOMIC_RELEASE, __HIP_MEMORY_SCOPE_AGENT);
    while (__hip_atomic_load(&bar[ph], __ATOMIC_RELAXED, __HIP_MEMORY_SCOPE_AGENT) < (int)gridDim.x)
      __builtin_amdgcn_s_sleep(16);
    __builtin_amdgcn_fence(__ATOMIC_ACQUIRE, "agent");
  }
  __syncthreads();
}

// ---------- gemm core: acc[2x2] (32Mx32N per wave-row-group) over NBK*128 k
template<int NBK>
__device__ __forceinline__ void gemm_core(const u16* abase, const float* bsrc,
                                          int K, Smem& sm, f32x4 acc[2][2]) {
  int tid = threadIdx.x, lane = tid & 63;
  int r0 = lane & 15, g = lane >> 4;
  int trow = tid >> 4, tcol = tid & 15;
  int swr = (trow & 7) << 4;
  int wofs = trow * 256 + ((tcol * 16) ^ swr);

  {
    f32x4 u = *(const f32x4*)bsrc;
    f32x4 v = *(const f32x4*)(bsrc + 4);
    *(bf16x8*)&sm.gemmBl[0][wofs] = cvt2(u, v);
  }
  bf16x8 a[2][2][4];
#pragma unroll
  for (int mi = 0; mi < 2; mi++)
#pragma unroll
    for (int kk = 0; kk < 4; kk++)
      a[0][mi][kk] = *(const bf16x8*)(abase + (long long)mi * 16 * K + kk * 32);

#pragma unroll
  for (int i = 0; i < 2; i++)
#pragma unroll
    for (int j = 0; j < 2; j++) acc[i][j] = (f32x4){0.f, 0.f, 0.f, 0.f};

  __syncthreads();

#pragma unroll
  for (int ibk = 0; ibk < NBK; ibk++) {
    const int cur = ibk & 1;
    const int nxt = cur ^ 1;
    f32x4 u, v;
    if (ibk + 1 < NBK) {
      int ko = (ibk + 1) * 128;
#pragma unroll
      for (int mi = 0; mi < 2; mi++)
#pragma unroll
        for (int kk = 0; kk < 4; kk++)
          a[nxt][mi][kk] = *(const bf16x8*)(abase + (long long)mi * 16 * K + ko + kk * 32);
      u = *(const f32x4*)(bsrc + ko);
      v = *(const f32x4*)(bsrc + ko + 4);
    }
    bf16x8 bfr[2][4];
#pragma unroll
    for (int nj = 0; nj < 2; nj++) {
      int row = nj * 16 + r0;
      int rb = row * 256, sw = (row & 7) << 4;
#pragma unroll
      for (int kk = 0; kk < 4; kk++)
        bfr[nj][kk] = *(const bf16x8*)&sm.gemmBl[cur][rb + ((kk * 64 + g * 16) ^ sw)];
    }
#pragma unroll
    for (int kk = 0; kk < 4; kk++)
#pragma unroll
      for (int mi = 0; mi < 2; mi++)
#pragma unroll
        for (int nj = 0; nj < 2; nj++)
          acc[mi][nj] = __builtin_amdgcn_mfma_f32_16x16x32_bf16(a[cur][mi][kk], bfr[nj][kk], acc[mi][nj], 0, 0, 0);
    if (ibk + 1 < NBK)
      *(bf16x8*)&sm.gemmBl[nxt][wofs] = cvt2(u, v);
    __syncthreads();
  }
}

// ---------- rms phase: h = src + sum(parts); x = bf16(h * rsqrt(sum h^2))
__device__ void phase_rms(const float* src, const float* parts, int np,
                          float* hout, u16* xout, Smem& sm) {
  int s = blockIdx.x, tid = threadIdx.x, lane = tid & 63, w = tid >> 6;
  f32x4 hv = (f32x4){0.f, 0.f, 0.f, 0.f};
  if (tid < 256) {
    hv = ((const f32x4*)(src + s * 1024))[tid];
    for (int p = 0; p < np; p++) {
      f32x4 pv = ((const f32x4*)(parts + (long long)p * 262144 + s * 1024))[tid];
      hv[0] += pv[0]; hv[1] += pv[1]; hv[2] += pv[2]; hv[3] += pv[3];
    }
  }
  float ss = hv[0]*hv[0] + hv[1]*hv[1] + hv[2]*hv[2] + hv[3]*hv[3];
#pragma unroll
  for (int off = 32; off > 0; off >>= 1) ss += __shfl_xor(ss, off, 64);
  if (lane == 0) sm.red[w] = ss;
  __syncthreads();
  ss = sm.red[0] + sm.red[1] + sm.red[2] + sm.red[3];
  float r = 1.0f / sqrtf(ss);
  if (tid < 256) {
    stg_wt_f4((float*)&((f32x4*)(hout + s * 1024))[tid], hv);
    u16x4 o;
#pragma unroll
    for (int c = 0; c < 4; c++) o[c] = f2bf(hv[c] * r);
    stg_wt_b8((u16*)&((u16x4*)xout)[s * 256 + tid], o);
  }
}

// ---------- final phase (writes kernel output: normal stores are fine)
__device__ void phase_final(const float* src, const float* parts,
                            const float* nw, float* out, Smem& sm) {
  int s = blockIdx.x, tid = threadIdx.x, lane = tid & 63, w = tid >> 6;
  f32x4 hv = (f32x4){0.f, 0.f, 0.f, 0.f};
  if (tid < 256) {
    hv = ((const f32x4*)(src + s * 1024))[tid];
    for (int p = 0; p < 8; p++) {
      f32x4 pv = ((const f32x4*)(parts + (long long)p * 262144 + s * 1024))[tid];
      hv[0] += pv[0]; hv[1] += pv[1]; hv[2] += pv[2]; hv[3] += pv[3];
    }
  }
  float ss = hv[0]*hv[0] + hv[1]*hv[1] + hv[2]*hv[2] + hv[3]*hv[3];
#pragma unroll
  for (int off = 32; off > 0; off >>= 1) ss += __shfl_xor(ss, off, 64);
  if (lane == 0) sm.red[w] = ss;
  __syncthreads();
  ss = sm.red[0] + sm.red[1] + sm.red[2] + sm.red[3];
  float r = 1.0f / sqrtf(ss * (1.0f / 1024.0f) + 1e-6f);
  if (tid < 256) {
    f32x4 wv = ((const f32x4*)nw)[tid];
    f32x4 o;
    o[0]=hv[0]*r*wv[0]; o[1]=hv[1]*r*wv[1]; o[2]=hv[2]*r*wv[2]; o[3]=hv[3]*r*wv[3];
    ((f32x4*)(out + s * 1024))[tid] = o;
  }
}

// ---------- transpose one 64x64 tile of past K or V
__device__ void transpose_unit(int unit, const float* pk, const float* pv,
                               u16* Kb, u16* Vb, Smem& sm) {
  int xt = unit & 31, rest = unit >> 5;
  int kvh = rest & 1, z = rest >> 1;
  int l = z >> 1, part = z & 1;
  int lk = l * 2 + kvh;
  int t0 = xt * 64, tid = threadIdx.x;
  if (part == 0) {
    const float* src = pk + (long long)lk * 131072;           // [d][t]
#pragma unroll
    for (int r = 0; r < 8; r++) {
      int idx = r * 512 + tid; int d = idx >> 6, t = idx & 63;
      sm.ttile[d][t] = src[d * 2048 + t0 + t];
    }
    __syncthreads();
    u16* dst = Kb + (long long)lk * 147456;                   // [t][d]
#pragma unroll
    for (int r = 0; r < 8; r++) {
      int idx = r * 512 + tid; int t = idx >> 6, d = idx & 63;
      stg_wt_u16(dst + (t0 + t) * 64 + d, f2bf(sm.ttile[d][t]));
    }
  } else {
    const float* src = pv + (long long)lk * 131072;           // [t][d]
#pragma unroll
    for (int r = 0; r < 8; r++) {
      int idx = r * 512 + tid; int t = idx >> 6, d = idx & 63;
      sm.ttile[t][d] = src[(t0 + t) * 64 + d];
    }
    __syncthreads();
    u16* dst = Vb + (long long)lk * 147456;                   // [d][t]
#pragma unroll
    for (int r = 0; r < 8; r++) {
      int idx = r * 512 + tid; int d = idx >> 6, t = idx & 63;
      stg_wt_u16(dst + d * 2304 + t0 + t, f2bf(sm.ttile[t][d]));
    }
  }
  __syncthreads();
}

// ---------- flash attention phase: block = (qt 0..15, hh 0..15); 8 waves x 288 T
struct KV { bf16x8 kf[2][2]; bf16x8 vf[4]; };

__device__ void phase_flash(const u16* qb, const u16* Kb2, const u16* Vb2,
                            u16* oacc, Smem& sm) {
  int bid = blockIdx.x, tid = threadIdx.x, lane = tid & 63, w = tid >> 6;
  int g = lane >> 4, r0 = lane & 15;
  int hh = bid & 15, qt = bid >> 4;
  int s0 = qt * 16, kvh = hh >> 3;

  const u16* Q  = qb  + hh * 16384;
  const u16* Kh = Kb2 + kvh * 147456;
  const u16* Vh = Vb2 + kvh * 147456;

  bf16x8 qf[2];
#pragma unroll
  for (int kk = 0; kk < 2; kk++)
    qf[kk] = *(const bf16x8*)(Q + (s0 + r0) * 64 + kk * 32 + g * 8);

  f32x4 O[4];
#pragma unroll
  for (int dj = 0; dj < 4; dj++) O[dj] = (f32x4){0.f, 0.f, 0.f, 0.f};
  float m = -1e30f, l = 0.f;

  int t0s = w * 288;

  auto loadkv = [&](KV& d, int t0) {
#pragma unroll
    for (int tj = 0; tj < 2; tj++)
#pragma unroll
      for (int kk = 0; kk < 2; kk++)
        d.kf[tj][kk] = *(const bf16x8*)(Kh + (t0 + tj * 16 + r0) * 64 + kk * 32 + g * 8);
#pragma unroll
    for (int dj = 0; dj < 4; dj++)
      d.vf[dj] = *(const bf16x8*)(Vh + (dj * 16 + r0) * 2304 + t0 + g * 8);
  };

  auto step = [&](KV& kv, int t0) {
    f32x4 sc[2];
#pragma unroll
    for (int tj = 0; tj < 2; tj++) {
      f32x4 z = (f32x4){0.f, 0.f, 0.f, 0.f};
      z = __builtin_amdgcn_mfma_f32_16x16x32_bf16(kv.kf[tj][0], qf[0], z, 0, 0, 0);
      z = __builtin_amdgcn_mfma_f32_16x16x32_bf16(kv.kf[tj][1], qf[1], z, 0, 0, 0);
      sc[tj] = z;
    }
    if (t0 + 31 > 2048 + s0) {
#pragma unroll
      for (int tj = 0; tj < 2; tj++)
#pragma unroll
        for (int q = 0; q < 4; q++) {
          int tg = t0 + tj * 16 + g * 4 + q;
          int sg = s0 + r0;
          if (tg > 2048 + sg) sc[tj][q] = -1e30f;
        }
    }
    float rm = -1e30f;
#pragma unroll
    for (int tj = 0; tj < 2; tj++)
#pragma unroll
      for (int q = 0; q < 4; q++) rm = fmaxf(rm, sc[tj][q]);
    rm = fmaxf(rm, __shfl_xor(rm, 16, 64));
    rm = fmaxf(rm, __shfl_xor(rm, 32, 64));
    float mn = fmaxf(m, rm);
    float sca = __expf(m - mn);
    float rs = 0.f;
#pragma unroll
    for (int tj = 0; tj < 2; tj++)
#pragma unroll
      for (int q = 0; q < 4; q++) {
        sc[tj][q] = __expf(sc[tj][q] - mn);
        rs += sc[tj][q];
      }
    rs += __shfl_xor(rs, 16, 64);
    rs += __shfl_xor(rs, 32, 64);
    l = l * sca + rs;
    m = mn;
#pragma unroll
    for (int dj = 0; dj < 4; dj++) {
      O[dj][0] *= sca; O[dj][1] *= sca; O[dj][2] *= sca; O[dj][3] *= sca;
    }
#pragma unroll
    for (int tj = 0; tj < 2; tj++) {
      u16x4 pw;
#pragma unroll
      for (int q = 0; q < 4; q++) pw[q] = f2bf(sc[tj][q]);
      *(u16x4*)&sm.fl.Plds[w][r0][tj * 16 + g * 4] = pw;
    }
    u16x4 plo = *(const u16x4*)&sm.fl.Plds[w][r0][g * 8];
    u16x4 phi = *(const u16x4*)&sm.fl.Plds[w][r0][g * 8 + 4];
    union { bf16x8 v; u16x4 h[2]; } pu;
    pu.h[0] = plo; pu.h[1] = phi;
#pragma unroll
    for (int dj = 0; dj < 4; dj++)
      O[dj] = __builtin_amdgcn_mfma_f32_16x16x32_bf16(kv.vf[dj], pu.v, O[dj], 0, 0, 0);
  };

  KV ba, bb;
  loadkv(ba, t0s);
#pragma unroll 1
  for (int p = 0; p < 4; p++) {
    int t0 = t0s + p * 64;
    loadkv(bb, t0 + 32);
    step(ba, t0);
    loadkv(ba, t0 + 64);
    step(bb, t0 + 32);
  }
  step(ba, t0s + 256);

#pragma unroll
  for (int dj = 0; dj < 4; dj++)
    *(f32x4*)&sm.fl.Osh[w][r0][dj * 16 + g * 4] = O[dj];
  if (g == 0) { sm.fl.msh[w][r0] = m; sm.fl.lsh[w][r0] = l; }
  __syncthreads();

  if (tid < 256) {
    int row = tid >> 4, c0 = (tid & 15) * 4;
    float M = -1e30f;
#pragma unroll
    for (int w8 = 0; w8 < 8; w8++) M = fmaxf(M, sm.fl.msh[w8][row]);
    float L = 0.f;
    float a0 = 0.f, a1 = 0.f, a2 = 0.f, a3 = 0.f;
#pragma unroll
    for (int w8 = 0; w8 < 8; w8++) {
      float e = __expf(sm.fl.msh[w8][row] - M);
      L += sm.fl.lsh[w8][row] * e;
      f32x4 ov = *(const f32x4*)&sm.fl.Osh[w8][row][c0];
      a0 += e * ov[0]; a1 += e * ov[1]; a2 += e * ov[2]; a3 += e * ov[3];
    }
    float inv = 1.0f / L;
    u16x4 o4;
    o4[0] = f2bf(a0 * inv); o4[1] = f2bf(a1 * inv);
    o4[2] = f2bf(a2 * inv); o4[3] = f2bf(a3 * inv);
    stg_wt_b8(oacc + (long long)(s0 + row) * 1024 + hh * 64 + c0, o4);
  }
}

// ---------- the megakernel ----------
__global__ __launch_bounds__(512, 2) void mega(MegaArgs A) {
  __shared__ Smem sm;
  int* bar = A.bar;
  int ph = 0;
  const int bid = blockIdx.x, tid = threadIdx.x;
  const int lane = tid & 63, w = tid >> 6;
  const int r0 = lane & 15, g = lane >> 4;
  const int trow = tid >> 4, tcol = tid & 15;
  const int rr = (lane >> 4) << 2;

  char* ws = A.ws;
  float* h    = (float*)(ws);
  u16*   x    = (u16*)(ws + 1048576);
  float* Pq   = (float*)(ws + 1572864);       // 4 x [256][1280]
  float* Po   = (float*)(ws + 6815744);       // 8 x [256][1024]
  float* Pd   = (float*)(ws + 15204352);      // 8 x [256][1024]
  u16*   y    = (u16*)(ws + 23592960);        // [256][4096]
  u16*   oacc = (u16*)(ws + 25690112);        // [256][1024]
  u16*   qb   = (u16*)(ws + 26214400);        // [16][256][64]
  u16*   Kb   = (u16*)(ws + 26738688);        // [8][2][2304][64]
  u16*   Vb   = (u16*)(ws + 31457280);        // [8][2][64][2304]

  // phase T: transpose all past K/V (1024 tiles / 256 blocks)
  for (int u = 0; u < 4; u++)
    transpose_unit(bid * 4 + u, A.pk, A.pv, Kb, Vb, sm);
  gsync(bar, ph++);

  for (int l = 0; l < 8; l++) {
    const float* qkvw_l = A.qkvw + (long long)l * 1310720;
    const float* ow_l   = A.ow   + (long long)l * 1048576;
    const float* guw_l  = A.guw  + (long long)l * 8388608;
    const float* dw_l   = A.dw   + (long long)l * 4194304;
    u16* Kbl = Kb + (long long)l * 294912;
    u16* Vbl = Vb + (long long)l * 294912;

    // P0: residual(+down partials) + rmsnorm
    phase_rms(l == 0 ? A.hs : h, Pd, l == 0 ? 0 : 8, h, x, sm);
    gsync(bar, ph++);

    // P1: qkv GEMM, 40 n-tiles x 4 ksplit = 160 units
    if (bid < 160) {
      int nt = bid % 40, slab = bid / 40;
      int n0 = nt * 32, kb = slab * 256;
      const u16* abase = x + (long long)(w * 32 + r0) * 1024 + g * 8 + kb;
      const float* bsrc = qkvw_l + (long long)(n0 + trow) * 1024 + kb + tcol * 8;
      f32x4 acc[2][2];
      gemm_core<2>(abase, bsrc, 1024, sm, acc);
      float* dst = Pq + (long long)slab * 327680;
#pragma unroll
      for (int mi = 0; mi < 2; mi++)
#pragma unroll
        for (int nj = 0; nj < 2; nj++)
#pragma unroll
          for (int q = 0; q < 4; q++) {
            int row = w * 32 + mi * 16 + rr + q;
            stg_wt_f1(dst + row * 1280 + n0 + nj * 16 + r0, acc[mi][nj][q]);
          }
    }
    gsync(bar, ph++);

    // P2: rope + scatter (sums 4 qkv partials)
    {
      int s = bid;
      for (int i = tid; i < 1280; i += 512) {
        int hh = i >> 6, d = i & 63;
        long long o0 = (long long)s * 1280;
        float v = Pq[o0 + i] + Pq[327680 + o0 + i] + Pq[655360 + o0 + i] + Pq[983040 + o0 + i];
        if (hh < 18) {
          int j = (hh << 6) | ((d + 32) & 63);
          float vr = Pq[o0 + j] + Pq[327680 + o0 + j] + Pq[655360 + o0 + j] + Pq[983040 + o0 + j];
          v = v * A.rc[s * 64 + d] + vr * A.rs[s * 64 + d];
          if (hh < 16) stg_wt_u16(qb + hh * 16384 + s * 64 + d, f2bf(v));
          else         stg_wt_u16(Kbl + (hh - 16) * 147456 + (2048 + s) * 64 + d, f2bf(v));
        } else {
          stg_wt_u16(Vbl + (hh - 18) * 147456 + d * 2304 + 2048 + s, f2bf(v));
        }
      }
    }
    gsync(bar, ph++);

    // P3: flash attention (256 units exactly)
    phase_flash(qb, Kbl, Vbl, oacc, sm);
    gsync(bar, ph++);

    // P4: o-proj GEMM, 32 n-tiles x 8 ksplit = 256 units
    {
      int n_idx = bid & 31, slab = bid >> 5;
      int n0 = n_idx * 32, kb = slab * 128;
      const u16* abase = oacc + (long long)(w * 32 + r0) * 1024 + g * 8 + kb;
      const float* bsrc = ow_l + (long long)(n0 + trow) * 1024 + kb + tcol * 8;
      f32x4 acc[2][2];
      gemm_core<1>(abase, bsrc, 1024, sm, acc);
      float* dst = Po + (long long)slab * 262144;
#pragma unroll
      for (int mi = 0; mi < 2; mi++)
#pragma unroll
        for (int nj = 0; nj < 2; nj++)
#pragma unroll
          for (int q = 0; q < 4; q++) {
            int row = w * 32 + mi * 16 + rr + q;
            stg_wt_f1(dst + row * 1024 + n0 + nj * 16 + r0, acc[mi][nj][q]);
          }
    }
    gsync(bar, ph++);

    // P5: residual(o partials) + rmsnorm
    phase_rms(h, Po, 8, h, x, sm);
    gsync(bar, ph++);

    // P6: gate_up GEMM + fused silu*up -> y ; unit = 16-col pair, 256 units
    {
      int n0 = bid * 16;
      const u16* abase = x + (long long)(w * 32 + r0) * 1024 + g * 8;
      const float* brow = (trow < 16)
          ? (guw_l + (long long)(n0 + trow) * 1024)
          : (guw_l + (long long)(4096 + n0 + trow - 16) * 1024);
      const float* bsrc = brow + tcol * 8;
      f32x4 acc[2][2];
      gemm_core<8>(abase, bsrc, 1024, sm, acc);
#pragma unroll
      for (int mi = 0; mi < 2; mi++)
#pragma unroll
        for (int q = 0; q < 4; q++) {
          int row = w * 32 + mi * 16 + rr + q;
          float gv = acc[mi][0][q], uv = acc[mi][1][q];
          stg_wt_u16(y + (long long)row * 4096 + n0 + r0,
                     f2bf((gv / (1.0f + __expf(-gv))) * uv));
        }
    }
    gsync(bar, ph++);

    // P7: down GEMM, 32 n-tiles x 8 ksplit = 256 units
    {
      int n_idx = bid & 31, slab = bid >> 5;
      int n0 = n_idx * 32, kb = slab * 512;
      const u16* abase = y + (long long)(w * 32 + r0) * 4096 + g * 8 + kb;
      const float* bsrc = dw_l + (long long)(n0 + trow) * 4096 + kb + tcol * 8;
      f32x4 acc[2][2];
      gemm_core<4>(abase, bsrc, 4096, sm, acc);
      float* dst = Pd + (long long)slab * 262144;
#pragma unroll
      for (int mi = 0; mi < 2; mi++)
#pragma unroll
        for (int nj = 0; nj < 2; nj++)
#pragma unroll
          for (int q = 0; q < 4; q++) {
            int row = w * 32 + mi * 16 + rr + q;
            stg_wt_f1(dst + row * 1024 + n0 + nj * 16 + r0, acc[mi][nj][q]);
          }
    }
    gsync(bar, ph++);
  }

  phase_final(h, Pd, A.nw, A.out, sm);
}

// ---------------- launch ----------------
extern "C" void kernel_launch(void* const* d_in, const int* in_sizes, int n_in,
                              void* d_out, int out_size, void* d_ws, size_t ws_size,
                              hipStream_t stream) {
  (void)in_sizes; (void)n_in; (void)out_size; (void)ws_size;
  MegaArgs ma;
  ma.hs   = (const float*)d_in[0];
  ma.rc   = (const float*)d_in[1];
  ma.rs   = (const float*)d_in[2];
  ma.pk   = (const float*)d_in[4];
  ma.pv   = (const float*)d_in[5];
  ma.qkvw = (const float*)d_in[6];
  ma.ow   = (const float*)d_in[7];
  ma.guw  = (const float*)d_in[8];
  ma.dw   = (const float*)d_in[9];
  ma.nw   = (const float*)d_in[10];
  ma.out  = (float*)d_out;
  ma.ws   = (char*)d_ws;
  ma.bar  = (int*)((char*)d_ws + 36175872);

  hipMemsetAsync((char*)d_ws + 36175872, 0, 1024, stream);
  void* kargs[] = { (void*)&ma };
  hipLaunchCooperativeKernel((const void*)mega, dim3(256), dim3(512), kargs, 0, stream);
}

// Round 8
// 1276.976 us; speedup vs baseline: 2.1288x; 1.2382x over previous
//
#include <hip/hip_runtime.h>
#include <hip/hip_bf16.h>

typedef __attribute__((ext_vector_type(4))) float f32x4;
typedef __attribute__((ext_vector_type(8))) __bf16 bf16x8;
typedef unsigned short u16;
typedef __attribute__((ext_vector_type(4))) unsigned short u16x4;

__device__ __forceinline__ u16 f2bf(float f) {
  __bf16 h = (__bf16)f;
  return __builtin_bit_cast(u16, h);
}

__device__ __forceinline__ bf16x8 cvt2(f32x4 x, f32x4 y) {
  bf16x8 r;
  r[0] = (__bf16)x[0]; r[1] = (__bf16)x[1]; r[2] = (__bf16)x[2]; r[3] = (__bf16)x[3];
  r[4] = (__bf16)y[0]; r[5] = (__bf16)y[1]; r[6] = (__bf16)y[2]; r[7] = (__bf16)y[3];
  return r;
}

// ---------- write-through (L2-bypass) stores for cross-block intermediates.
__device__ __forceinline__ void stg_wt_f4(float* p, f32x4 v) {
  asm volatile("global_store_dwordx4 %0, %1, off sc0 sc1" :: "v"(p), "v"(v) : "memory");
}
__device__ __forceinline__ void stg_wt_f1(float* p, float v) {
  asm volatile("global_store_dword %0, %1, off sc0 sc1" :: "v"(p), "v"(v) : "memory");
}
__device__ __forceinline__ void stg_wt_u16(u16* p, unsigned v) {
  asm volatile("global_store_short %0, %1, off sc0 sc1" :: "v"(p), "v"(v) : "memory");
}
__device__ __forceinline__ void stg_wt_b8(u16* p, u16x4 v) {
  unsigned long long q = __builtin_bit_cast(unsigned long long, v);
  asm volatile("global_store_dwordx2 %0, %1, off sc0 sc1" :: "v"(p), "v"(q) : "memory");
}

union Smem {
  char gemmBl[2][8192];                       // 16 KB (gemm B tile, dbuf, swizzled)
  struct {
    u16 Plds[8][16][36];                      // 9216 B
    float Osh[8][16][68];                     // 34816 B
    float msh[8][16];
    float lsh[8][16];                         // 1024 B
  } fl;                                       // 45056 B
  float ttile[64][65];                        // 16640 B
  float red[8];
};

struct MegaArgs {
  const float *hs, *rc, *rs, *pk, *pv, *qkvw, *ow, *guw, *dw, *nw;
  float* out;
  char* ws;
  int* bar;
};

// ---------- grid barrier v3 (256 co-resident blocks, cooperative launch)
// All intermediate stores are sc0sc1 write-through, and __syncthreads drains
// each wave's vmcnt => data is at the coherence point by arrive time => NO
// release cache-op. Arrive/spin are RELAXED (no cache maintenance).
// Cache invalidate for the cached-read paths is done ONCE PER XCD by an
// elected leader (buffer_inv sc1 = L1+L2 of this XCD), instead of 256
// redundant fence-acquires serializing on each XCD's L2 tag-walk hardware
// (the ~26us/barrier cost of rounds 6-7). Non-leaders invalidate only their
// own CU's L1 (buffer_inv) and wait on a per-XCD done flag.
__device__ __forceinline__ void gsync(int* bar, int* flags, int ph, int xcd, int lead) {
  __syncthreads();                       // drains vmcnt/lgkmcnt per wave
  if (threadIdx.x == 0) {
    __hip_atomic_fetch_add(&bar[ph], 1, __ATOMIC_RELAXED, __HIP_MEMORY_SCOPE_AGENT);
    while (__hip_atomic_load(&bar[ph], __ATOMIC_RELAXED, __HIP_MEMORY_SCOPE_AGENT) < (int)gridDim.x)
      __builtin_amdgcn_s_sleep(8);
    if (lead) {
      asm volatile("buffer_inv sc1\n\tbuffer_inv\n\ts_waitcnt vmcnt(0)" ::: "memory");
      __hip_atomic_store(&flags[ph * 8 + xcd], 1, __ATOMIC_RELAXED, __HIP_MEMORY_SCOPE_AGENT);
    } else {
      asm volatile("buffer_inv" ::: "memory");   // own-CU L1 only
      while (__hip_atomic_load(&flags[ph * 8 + xcd], __ATOMIC_RELAXED, __HIP_MEMORY_SCOPE_AGENT) == 0)
        __builtin_amdgcn_s_sleep(1);
    }
  }
  __syncthreads();
}

// ---------- gemm core: acc[2x2] (32Mx32N per wave-row-group) over NBK*128 k
template<int NBK>
__device__ __forceinline__ void gemm_core(const u16* abase, const float* bsrc,
                                          int K, Smem& sm, f32x4 acc[2][2]) {
  int tid = threadIdx.x, lane = tid & 63;
  int r0 = lane & 15, g = lane >> 4;
  int trow = tid >> 4, tcol = tid & 15;
  int swr = (trow & 7) << 4;
  int wofs = trow * 256 + ((tcol * 16) ^ swr);

  {
    f32x4 u = *(const f32x4*)bsrc;
    f32x4 v = *(const f32x4*)(bsrc + 4);
    *(bf16x8*)&sm.gemmBl[0][wofs] = cvt2(u, v);
  }
  bf16x8 a[2][2][4];
#pragma unroll
  for (int mi = 0; mi < 2; mi++)
#pragma unroll
    for (int kk = 0; kk < 4; kk++)
      a[0][mi][kk] = *(const bf16x8*)(abase + (long long)mi * 16 * K + kk * 32);

#pragma unroll
  for (int i = 0; i < 2; i++)
#pragma unroll
    for (int j = 0; j < 2; j++) acc[i][j] = (f32x4){0.f, 0.f, 0.f, 0.f};

  __syncthreads();

#pragma unroll
  for (int ibk = 0; ibk < NBK; ibk++) {
    const int cur = ibk & 1;
    const int nxt = cur ^ 1;
    f32x4 u, v;
    if (ibk + 1 < NBK) {
      int ko = (ibk + 1) * 128;
#pragma unroll
      for (int mi = 0; mi < 2; mi++)
#pragma unroll
        for (int kk = 0; kk < 4; kk++)
          a[nxt][mi][kk] = *(const bf16x8*)(abase + (long long)mi * 16 * K + ko + kk * 32);
      u = *(const f32x4*)(bsrc + ko);
      v = *(const f32x4*)(bsrc + ko + 4);
    }
    bf16x8 bfr[2][4];
#pragma unroll
    for (int nj = 0; nj < 2; nj++) {
      int row = nj * 16 + r0;
      int rb = row * 256, sw = (row & 7) << 4;
#pragma unroll
      for (int kk = 0; kk < 4; kk++)
        bfr[nj][kk] = *(const bf16x8*)&sm.gemmBl[cur][rb + ((kk * 64 + g * 16) ^ sw)];
    }
#pragma unroll
    for (int kk = 0; kk < 4; kk++)
#pragma unroll
      for (int mi = 0; mi < 2; mi++)
#pragma unroll
        for (int nj = 0; nj < 2; nj++)
          acc[mi][nj] = __builtin_amdgcn_mfma_f32_16x16x32_bf16(a[cur][mi][kk], bfr[nj][kk], acc[mi][nj], 0, 0, 0);
    if (ibk + 1 < NBK)
      *(bf16x8*)&sm.gemmBl[nxt][wofs] = cvt2(u, v);
    __syncthreads();
  }
}

// ---------- rms phase: h = src + sum(parts); x = bf16(h * rsqrt(sum h^2))
__device__ void phase_rms(const float* src, const float* parts, int np,
                          float* hout, u16* xout, Smem& sm) {
  int s = blockIdx.x, tid = threadIdx.x, lane = tid & 63, w = tid >> 6;
  f32x4 hv = (f32x4){0.f, 0.f, 0.f, 0.f};
  if (tid < 256) {
    hv = ((const f32x4*)(src + s * 1024))[tid];
    for (int p = 0; p < np; p++) {
      f32x4 pv = ((const f32x4*)(parts + (long long)p * 262144 + s * 1024))[tid];
      hv[0] += pv[0]; hv[1] += pv[1]; hv[2] += pv[2]; hv[3] += pv[3];
    }
  }
  float ss = hv[0]*hv[0] + hv[1]*hv[1] + hv[2]*hv[2] + hv[3]*hv[3];
#pragma unroll
  for (int off = 32; off > 0; off >>= 1) ss += __shfl_xor(ss, off, 64);
  if (lane == 0) sm.red[w] = ss;
  __syncthreads();
  ss = sm.red[0] + sm.red[1] + sm.red[2] + sm.red[3];
  float r = 1.0f / sqrtf(ss);
  if (tid < 256) {
    stg_wt_f4((float*)&((f32x4*)(hout + s * 1024))[tid], hv);
    u16x4 o;
#pragma unroll
    for (int c = 0; c < 4; c++) o[c] = f2bf(hv[c] * r);
    stg_wt_b8((u16*)&((u16x4*)xout)[s * 256 + tid], o);
  }
}

// ---------- final phase (writes kernel output: normal stores are fine)
__device__ void phase_final(const float* src, const float* parts,
                            const float* nw, float* out, Smem& sm) {
  int s = blockIdx.x, tid = threadIdx.x, lane = tid & 63, w = tid >> 6;
  f32x4 hv = (f32x4){0.f, 0.f, 0.f, 0.f};
  if (tid < 256) {
    hv = ((const f32x4*)(src + s * 1024))[tid];
    for (int p = 0; p < 8; p++) {
      f32x4 pv = ((const f32x4*)(parts + (long long)p * 262144 + s * 1024))[tid];
      hv[0] += pv[0]; hv[1] += pv[1]; hv[2] += pv[2]; hv[3] += pv[3];
    }
  }
  float ss = hv[0]*hv[0] + hv[1]*hv[1] + hv[2]*hv[2] + hv[3]*hv[3];
#pragma unroll
  for (int off = 32; off > 0; off >>= 1) ss += __shfl_xor(ss, off, 64);
  if (lane == 0) sm.red[w] = ss;
  __syncthreads();
  ss = sm.red[0] + sm.red[1] + sm.red[2] + sm.red[3];
  float r = 1.0f / sqrtf(ss * (1.0f / 1024.0f) + 1e-6f);
  if (tid < 256) {
    f32x4 wv = ((const f32x4*)nw)[tid];
    f32x4 o;
    o[0]=hv[0]*r*wv[0]; o[1]=hv[1]*r*wv[1]; o[2]=hv[2]*r*wv[2]; o[3]=hv[3]*r*wv[3];
    ((f32x4*)(out + s * 1024))[tid] = o;
  }
}

// ---------- transpose one 64x64 tile of past K or V
__device__ void transpose_unit(int unit, const float* pk, const float* pv,
                               u16* Kb, u16* Vb, Smem& sm) {
  int xt = unit & 31, rest = unit >> 5;
  int kvh = rest & 1, z = rest >> 1;
  int l = z >> 1, part = z & 1;
  int lk = l * 2 + kvh;
  int t0 = xt * 64, tid = threadIdx.x;
  if (part == 0) {
    const float* src = pk + (long long)lk * 131072;           // [d][t]
#pragma unroll
    for (int r = 0; r < 8; r++) {
      int idx = r * 512 + tid; int d = idx >> 6, t = idx & 63;
      sm.ttile[d][t] = src[d * 2048 + t0 + t];
    }
    __syncthreads();
    u16* dst = Kb + (long long)lk * 147456;                   // [t][d]
#pragma unroll
    for (int r = 0; r < 8; r++) {
      int idx = r * 512 + tid; int t = idx >> 6, d = idx & 63;
      stg_wt_u16(dst + (t0 + t) * 64 + d, f2bf(sm.ttile[d][t]));
    }
  } else {
    const float* src = pv + (long long)lk * 131072;           // [t][d]
#pragma unroll
    for (int r = 0; r < 8; r++) {
      int idx = r * 512 + tid; int t = idx >> 6, d = idx & 63;
      sm.ttile[t][d] = src[(t0 + t) * 64 + d];
    }
    __syncthreads();
    u16* dst = Vb + (long long)lk * 147456;                   // [d][t]
#pragma unroll
    for (int r = 0; r < 8; r++) {
      int idx = r * 512 + tid; int d = idx >> 6, t = idx & 63;
      stg_wt_u16(dst + d * 2304 + t0 + t, f2bf(sm.ttile[t][d]));
    }
  }
  __syncthreads();
}

// ---------- flash attention phase: block = (qt 0..15, hh 0..15); 8 waves x 288 T
struct KV { bf16x8 kf[2][2]; bf16x8 vf[4]; };

__device__ void phase_flash(const u16* qb, const u16* Kb2, const u16* Vb2,
                            u16* oacc, Smem& sm) {
  int bid = blockIdx.x, tid = threadIdx.x, lane = tid & 63, w = tid >> 6;
  int g = lane >> 4, r0 = lane & 15;
  int hh = bid & 15, qt = bid >> 4;
  int s0 = qt * 16, kvh = hh >> 3;

  const u16* Q  = qb  + hh * 16384;
  const u16* Kh = Kb2 + kvh * 147456;
  const u16* Vh = Vb2 + kvh * 147456;

  bf16x8 qf[2];
#pragma unroll
  for (int kk = 0; kk < 2; kk++)
    qf[kk] = *(const bf16x8*)(Q + (s0 + r0) * 64 + kk * 32 + g * 8);

  f32x4 O[4];
#pragma unroll
  for (int dj = 0; dj < 4; dj++) O[dj] = (f32x4){0.f, 0.f, 0.f, 0.f};
  float m = -1e30f, l = 0.f;

  int t0s = w * 288;

  auto loadkv = [&](KV& d, int t0) {
#pragma unroll
    for (int tj = 0; tj < 2; tj++)
#pragma unroll
      for (int kk = 0; kk < 2; kk++)
        d.kf[tj][kk] = *(const bf16x8*)(Kh + (t0 + tj * 16 + r0) * 64 + kk * 32 + g * 8);
#pragma unroll
    for (int dj = 0; dj < 4; dj++)
      d.vf[dj] = *(const bf16x8*)(Vh + (dj * 16 + r0) * 2304 + t0 + g * 8);
  };

  auto step = [&](KV& kv, int t0) {
    f32x4 sc[2];
#pragma unroll
    for (int tj = 0; tj < 2; tj++) {
      f32x4 z = (f32x4){0.f, 0.f, 0.f, 0.f};
      z = __builtin_amdgcn_mfma_f32_16x16x32_bf16(kv.kf[tj][0], qf[0], z, 0, 0, 0);
      z = __builtin_amdgcn_mfma_f32_16x16x32_bf16(kv.kf[tj][1], qf[1], z, 0, 0, 0);
      sc[tj] = z;
    }
    if (t0 + 31 > 2048 + s0) {
#pragma unroll
      for (int tj = 0; tj < 2; tj++)
#pragma unroll
        for (int q = 0; q < 4; q++) {
          int tg = t0 + tj * 16 + g * 4 + q;
          int sg = s0 + r0;
          if (tg > 2048 + sg) sc[tj][q] = -1e30f;
        }
    }
    float rm = -1e30f;
#pragma unroll
    for (int tj = 0; tj < 2; tj++)
#pragma unroll
      for (int q = 0; q < 4; q++) rm = fmaxf(rm, sc[tj][q]);
    rm = fmaxf(rm, __shfl_xor(rm, 16, 64));
    rm = fmaxf(rm, __shfl_xor(rm, 32, 64));
    float mn = fmaxf(m, rm);
    float sca = __expf(m - mn);
    float rs = 0.f;
#pragma unroll
    for (int tj = 0; tj < 2; tj++)
#pragma unroll
      for (int q = 0; q < 4; q++) {
        sc[tj][q] = __expf(sc[tj][q] - mn);
        rs += sc[tj][q];
      }
    rs += __shfl_xor(rs, 16, 64);
    rs += __shfl_xor(rs, 32, 64);
    l = l * sca + rs;
    m = mn;
#pragma unroll
    for (int dj = 0; dj < 4; dj++) {
      O[dj][0] *= sca; O[dj][1] *= sca; O[dj][2] *= sca; O[dj][3] *= sca;
    }
#pragma unroll
    for (int tj = 0; tj < 2; tj++) {
      u16x4 pw;
#pragma unroll
      for (int q = 0; q < 4; q++) pw[q] = f2bf(sc[tj][q]);
      *(u16x4*)&sm.fl.Plds[w][r0][tj * 16 + g * 4] = pw;
    }
    u16x4 plo = *(const u16x4*)&sm.fl.Plds[w][r0][g * 8];
    u16x4 phi = *(const u16x4*)&sm.fl.Plds[w][r0][g * 8 + 4];
    union { bf16x8 v; u16x4 h[2]; } pu;
    pu.h[0] = plo; pu.h[1] = phi;
#pragma unroll
    for (int dj = 0; dj < 4; dj++)
      O[dj] = __builtin_amdgcn_mfma_f32_16x16x32_bf16(kv.vf[dj], pu.v, O[dj], 0, 0, 0);
  };

  KV ba, bb;
  loadkv(ba, t0s);
#pragma unroll 1
  for (int p = 0; p < 4; p++) {
    int t0 = t0s + p * 64;
    loadkv(bb, t0 + 32);
    step(ba, t0);
    loadkv(ba, t0 + 64);
    step(bb, t0 + 32);
  }
  step(ba, t0s + 256);

#pragma unroll
  for (int dj = 0; dj < 4; dj++)
    *(f32x4*)&sm.fl.Osh[w][r0][dj * 16 + g * 4] = O[dj];
  if (g == 0) { sm.fl.msh[w][r0] = m; sm.fl.lsh[w][r0] = l; }
  __syncthreads();

  if (tid < 256) {
    int row = tid >> 4, c0 = (tid & 15) * 4;
    float M = -1e30f;
#pragma unroll
    for (int w8 = 0; w8 < 8; w8++) M = fmaxf(M, sm.fl.msh[w8][row]);
    float L = 0.f;
    float a0 = 0.f, a1 = 0.f, a2 = 0.f, a3 = 0.f;
#pragma unroll
    for (int w8 = 0; w8 < 8; w8++) {
      float e = __expf(sm.fl.msh[w8][row] - M);
      L += sm.fl.lsh[w8][row] * e;
      f32x4 ov = *(const f32x4*)&sm.fl.Osh[w8][row][c0];
      a0 += e * ov[0]; a1 += e * ov[1]; a2 += e * ov[2]; a3 += e * ov[3];
    }
    float inv = 1.0f / L;
    u16x4 o4;
    o4[0] = f2bf(a0 * inv); o4[1] = f2bf(a1 * inv);
    o4[2] = f2bf(a2 * inv); o4[3] = f2bf(a3 * inv);
    stg_wt_b8(oacc + (long long)(s0 + row) * 1024 + hh * 64 + c0, o4);
  }
}

// ---------- the megakernel ----------
__global__ __launch_bounds__(512, 2) void mega(MegaArgs A) {
  __shared__ Smem sm;
  __shared__ int leadSh;
  int* bar   = A.bar;          // [65]
  int* flags = A.bar + 256;    // [65*8]
  int* elect = A.bar + 960;    // [8]
  int ph = 0;
  const int bid = blockIdx.x, tid = threadIdx.x;
  const int lane = tid & 63, w = tid >> 6;
  const int r0 = lane & 15, g = lane >> 4;
  const int trow = tid >> 4, tcol = tid & 15;
  const int rr = (lane >> 4) << 2;

  // XCD id + one-time per-XCD leader election (first arriver leads)
  int xcd;
  asm volatile("s_getreg_b32 %0, hwreg(20, 0, 32)" : "=s"(xcd));  // HW_REG_XCC_ID
  xcd &= 7;
  if (tid == 0) {
    int old = __hip_atomic_fetch_add(&elect[xcd], 1, __ATOMIC_RELAXED, __HIP_MEMORY_SCOPE_AGENT);
    leadSh = (old == 0);
  }
  __syncthreads();
  const int lead = leadSh;

  char* ws = A.ws;
  float* h    = (float*)(ws);
  u16*   x    = (u16*)(ws + 1048576);
  float* Pq   = (float*)(ws + 1572864);       // 4 x [256][1280]
  float* Po   = (float*)(ws + 6815744);       // 8 x [256][1024]
  float* Pd   = (float*)(ws + 15204352);      // 8 x [256][1024]
  u16*   y    = (u16*)(ws + 23592960);        // [256][4096]
  u16*   oacc = (u16*)(ws + 25690112);        // [256][1024]
  u16*   qb   = (u16*)(ws + 26214400);        // [16][256][64]
  u16*   Kb   = (u16*)(ws + 26738688);        // [8][2][2304][64]
  u16*   Vb   = (u16*)(ws + 31457280);        // [8][2][64][2304]

  // phase T: transpose all past K/V (1024 tiles / 256 blocks)
  for (int u = 0; u < 4; u++)
    transpose_unit(bid * 4 + u, A.pk, A.pv, Kb, Vb, sm);
  gsync(bar, flags, ph++, xcd, lead);

  for (int l = 0; l < 8; l++) {
    const float* qkvw_l = A.qkvw + (long long)l * 1310720;
    const float* ow_l   = A.ow   + (long long)l * 1048576;
    const float* guw_l  = A.guw  + (long long)l * 8388608;
    const float* dw_l   = A.dw   + (long long)l * 4194304;
    u16* Kbl = Kb + (long long)l * 294912;
    u16* Vbl = Vb + (long long)l * 294912;

    // P0: residual(+down partials) + rmsnorm
    phase_rms(l == 0 ? A.hs : h, Pd, l == 0 ? 0 : 8, h, x, sm);
    gsync(bar, flags, ph++, xcd, lead);

    // P1: qkv GEMM, 40 n-tiles x 4 ksplit = 160 units
    if (bid < 160) {
      int nt = bid % 40, slab = bid / 40;
      int n0 = nt * 32, kb = slab * 256;
      const u16* abase = x + (long long)(w * 32 + r0) * 1024 + g * 8 + kb;
      const float* bsrc = qkvw_l + (long long)(n0 + trow) * 1024 + kb + tcol * 8;
      f32x4 acc[2][2];
      gemm_core<2>(abase, bsrc, 1024, sm, acc);
      float* dst = Pq + (long long)slab * 327680;
#pragma unroll
      for (int mi = 0; mi < 2; mi++)
#pragma unroll
        for (int nj = 0; nj < 2; nj++)
#pragma unroll
          for (int q = 0; q < 4; q++) {
            int row = w * 32 + mi * 16 + rr + q;
            stg_wt_f1(dst + row * 1280 + n0 + nj * 16 + r0, acc[mi][nj][q]);
          }
    }
    gsync(bar, flags, ph++, xcd, lead);

    // P2: rope + scatter (sums 4 qkv partials)
    {
      int s = bid;
      for (int i = tid; i < 1280; i += 512) {
        int hh = i >> 6, d = i & 63;
        long long o0 = (long long)s * 1280;
        float v = Pq[o0 + i] + Pq[327680 + o0 + i] + Pq[655360 + o0 + i] + Pq[983040 + o0 + i];
        if (hh < 18) {
          int j = (hh << 6) | ((d + 32) & 63);
          float vr = Pq[o0 + j] + Pq[327680 + o0 + j] + Pq[655360 + o0 + j] + Pq[983040 + o0 + j];
          v = v * A.rc[s * 64 + d] + vr * A.rs[s * 64 + d];
          if (hh < 16) stg_wt_u16(qb + hh * 16384 + s * 64 + d, f2bf(v));
          else         stg_wt_u16(Kbl + (hh - 16) * 147456 + (2048 + s) * 64 + d, f2bf(v));
        } else {
          stg_wt_u16(Vbl + (hh - 18) * 147456 + d * 2304 + 2048 + s, f2bf(v));
        }
      }
    }
    gsync(bar, flags, ph++, xcd, lead);

    // P3: flash attention (256 units exactly)
    phase_flash(qb, Kbl, Vbl, oacc, sm);
    gsync(bar, flags, ph++, xcd, lead);

    // P4: o-proj GEMM, 32 n-tiles x 8 ksplit = 256 units
    {
      int n_idx = bid & 31, slab = bid >> 5;
      int n0 = n_idx * 32, kb = slab * 128;
      const u16* abase = oacc + (long long)(w * 32 + r0) * 1024 + g * 8 + kb;
      const float* bsrc = ow_l + (long long)(n0 + trow) * 1024 + kb + tcol * 8;
      f32x4 acc[2][2];
      gemm_core<1>(abase, bsrc, 1024, sm, acc);
      float* dst = Po + (long long)slab * 262144;
#pragma unroll
      for (int mi = 0; mi < 2; mi++)
#pragma unroll
        for (int nj = 0; nj < 2; nj++)
#pragma unroll
          for (int q = 0; q < 4; q++) {
            int row = w * 32 + mi * 16 + rr + q;
            stg_wt_f1(dst + row * 1024 + n0 + nj * 16 + r0, acc[mi][nj][q]);
          }
    }
    gsync(bar, flags, ph++, xcd, lead);

    // P5: residual(o partials) + rmsnorm
    phase_rms(h, Po, 8, h, x, sm);
    gsync(bar, flags, ph++, xcd, lead);

    // P6: gate_up GEMM + fused silu*up -> y ; unit = 16-col pair, 256 units
    {
      int n0 = bid * 16;
      const u16* abase = x + (long long)(w * 32 + r0) * 1024 + g * 8;
      const float* brow = (trow < 16)
          ? (guw_l + (long long)(n0 + trow) * 1024)
          : (guw_l + (long long)(4096 + n0 + trow - 16) * 1024);
      const float* bsrc = brow + tcol * 8;
      f32x4 acc[2][2];
      gemm_core<8>(abase, bsrc, 1024, sm, acc);
#pragma unroll
      for (int mi = 0; mi < 2; mi++)
#pragma unroll
        for (int q = 0; q < 4; q++) {
          int row = w * 32 + mi * 16 + rr + q;
          float gv = acc[mi][0][q], uv = acc[mi][1][q];
          stg_wt_u16(y + (long long)row * 4096 + n0 + r0,
                     f2bf((gv / (1.0f + __expf(-gv))) * uv));
        }
    }
    gsync(bar, flags, ph++, xcd, lead);

    // P7: down GEMM, 32 n-tiles x 8 ksplit = 256 units
    {
      int n_idx = bid & 31, slab = bid >> 5;
      int n0 = n_idx * 32, kb = slab * 512;
      const u16* abase = y + (long long)(w * 32 + r0) * 4096 + g * 8 + kb;
      const float* bsrc = dw_l + (long long)(n0 + trow) * 4096 + kb + tcol * 8;
      f32x4 acc[2][2];
      gemm_core<4>(abase, bsrc, 4096, sm, acc);
      float* dst = Pd + (long long)slab * 262144;
#pragma unroll
      for (int mi = 0; mi < 2; mi++)
#pragma unroll
        for (int nj = 0; nj < 2; nj++)
#pragma unroll
          for (int q = 0; q < 4; q++) {
            int row = w * 32 + mi * 16 + rr + q;
            stg_wt_f1(dst + row * 1024 + n0 + nj * 16 + r0, acc[mi][nj][q]);
          }
    }
    gsync(bar, flags, ph++, xcd, lead);
  }

  phase_final(h, Pd, A.nw, A.out, sm);
}

// ---------------- launch ----------------
extern "C" void kernel_launch(void* const* d_in, const int* in_sizes, int n_in,
                              void* d_out, int out_size, void* d_ws, size_t ws_size,
                              hipStream_t stream) {
  (void)in_sizes; (void)n_in; (void)out_size; (void)ws_size;
  MegaArgs ma;
  ma.hs   = (const float*)d_in[0];
  ma.rc   = (const float*)d_in[1];
  ma.rs   = (const float*)d_in[2];
  ma.pk   = (const float*)d_in[4];
  ma.pv   = (const float*)d_in[5];
  ma.qkvw = (const float*)d_in[6];
  ma.ow   = (const float*)d_in[7];
  ma.guw  = (const float*)d_in[8];
  ma.dw   = (const float*)d_in[9];
  ma.nw   = (const float*)d_in[10];
  ma.out  = (float*)d_out;
  ma.ws   = (char*)d_ws;
  ma.bar  = (int*)((char*)d_ws + 36175872);

  hipMemsetAsync((char*)d_ws + 36175872, 0, 4096, stream);
  void* kargs[] = { (void*)&ma };
  hipLaunchCooperativeKernel((const void*)mega, dim3(256), dim3(512), kargs, 0, stream);
}

// Round 10
// 680.672 us; speedup vs baseline: 3.9937x; 1.8761x over previous
//
#include <hip/hip_runtime.h>
#include <hip/hip_bf16.h>

typedef __attribute__((ext_vector_type(4))) float f32x4;
typedef __attribute__((ext_vector_type(8))) __bf16 bf16x8;
typedef unsigned short u16;
typedef __attribute__((ext_vector_type(4))) unsigned short u16x4;

__device__ __forceinline__ u16 f2bf(float f) {
  __bf16 h = (__bf16)f;
  return __builtin_bit_cast(u16, h);
}

__device__ __forceinline__ bf16x8 cvt2(f32x4 x, f32x4 y) {
  bf16x8 r;
  r[0] = (__bf16)x[0]; r[1] = (__bf16)x[1]; r[2] = (__bf16)x[2]; r[3] = (__bf16)x[3];
  r[4] = (__bf16)y[0]; r[5] = (__bf16)y[1]; r[6] = (__bf16)y[2]; r[7] = (__bf16)y[3];
  return r;
}

// ---------------- weight GEMM: C[256 x N] = A[256 x K]bf16 @ B[N x K]f32^T
// 512 thr = 8 waves partitioning M (wave w: rows w*32..w*32+32). BN=32, BK=128.
// B: fp32 global -> regs -> bf16 -> swizzled LDS (double-buffered).
// A: direct global bf16, ping-pong register prefetch.
// grid.x = N/32, grid.y = ksplit index (NBK*128 k each).
// CMODE: 0 = f32 store to partial slab (offset blockIdx.y*256*ldc), 1 = bf16 store.
template<int CMODE, int NBK>
__global__ __launch_bounds__(512) void gemmW(
    const u16* __restrict__ A, const float* __restrict__ B,
    void* __restrict__ Cv, int K, int ldc)
{
  __shared__ char Bl[2][8192];
  int n0 = blockIdx.x * 32;
  int kb = blockIdx.y * (NBK * 128);
  int tid = threadIdx.x, lane = tid & 63, w = tid >> 6;
  int r0 = lane & 15, g = lane >> 4;
  int trow = tid >> 4, tcol = tid & 15;

  const float* bsrc = B + (long long)(n0 + trow) * K + kb + tcol * 8;
  const u16* abase = A + (long long)(w * 32 + r0) * K + kb + g * 8;
  int swr = (trow & 7) << 4;
  int wofs = trow * 256 + ((tcol * 16) ^ swr);

  {
    f32x4 u = *(const f32x4*)bsrc;
    f32x4 v = *(const f32x4*)(bsrc + 4);
    *(bf16x8*)&Bl[0][wofs] = cvt2(u, v);
  }
  bf16x8 a[2][2][4];
#pragma unroll
  for (int mi = 0; mi < 2; mi++)
#pragma unroll
    for (int kk = 0; kk < 4; kk++)
      a[0][mi][kk] = *(const bf16x8*)(abase + (long long)mi * 16 * K + kk * 32);

  f32x4 acc[2][2];
#pragma unroll
  for (int i = 0; i < 2; i++)
#pragma unroll
    for (int j = 0; j < 2; j++) acc[i][j] = (f32x4){0.f, 0.f, 0.f, 0.f};

  __syncthreads();

#pragma unroll
  for (int ibk = 0; ibk < NBK; ibk++) {
    const int cur = ibk & 1;
    const int nxt = cur ^ 1;
    f32x4 u, v;
    if (ibk + 1 < NBK) {
      int ko = (ibk + 1) * 128;
#pragma unroll
      for (int mi = 0; mi < 2; mi++)
#pragma unroll
        for (int kk = 0; kk < 4; kk++)
          a[nxt][mi][kk] = *(const bf16x8*)(abase + (long long)mi * 16 * K + ko + kk * 32);
      u = *(const f32x4*)(bsrc + ko);
      v = *(const f32x4*)(bsrc + ko + 4);
    }
    bf16x8 bfr[2][4];
#pragma unroll
    for (int nj = 0; nj < 2; nj++) {
      int row = nj * 16 + r0;
      int rb = row * 256, sw = (row & 7) << 4;
#pragma unroll
      for (int kk = 0; kk < 4; kk++)
        bfr[nj][kk] = *(const bf16x8*)&Bl[cur][rb + ((kk * 64 + g * 16) ^ sw)];
    }
#pragma unroll
    for (int kk = 0; kk < 4; kk++)
#pragma unroll
      for (int mi = 0; mi < 2; mi++)
#pragma unroll
        for (int nj = 0; nj < 2; nj++)
          acc[mi][nj] = __builtin_amdgcn_mfma_f32_16x16x32_bf16(a[cur][mi][kk], bfr[nj][kk], acc[mi][nj], 0, 0, 0);
    if (ibk + 1 < NBK)
      *(bf16x8*)&Bl[nxt][wofs] = cvt2(u, v);
    __syncthreads();
  }

  long long co = (long long)blockIdx.y * 256 * ldc;
  int rr = (lane >> 4) << 2;
#pragma unroll
  for (int mi = 0; mi < 2; mi++)
#pragma unroll
    for (int nj = 0; nj < 2; nj++)
#pragma unroll
      for (int q = 0; q < 4; q++) {
        int row = w * 32 + mi * 16 + rr + q;
        long long idx = co + (long long)row * ldc + n0 + nj * 16 + r0;
        float vv = acc[mi][nj][q];
        if (CMODE == 0) ((float*)Cv)[idx] = vv;
        else            ((u16*)Cv)[idx] = f2bf(vv);
      }
}

// ---------------- gate_up GEMM + fused silu: y[256x4096]bf16
// grid (256,1). Block covers 16 gate cols (n0..n0+16) + matching 16 up cols.
// B-tile rows 0..15 = gate rows n0+trow, rows 16..31 = up rows 4096+n0+trow-16.
// acc[mi][0] = gate, acc[mi][1] = up  ->  y = silu(gate)*up.
__global__ __launch_bounds__(512) void gemmGU(
    const u16* __restrict__ A, const float* __restrict__ B,
    u16* __restrict__ y)
{
  const int K = 1024, NBK = 8;
  __shared__ char Bl[2][8192];
  int n0 = blockIdx.x * 16;
  int tid = threadIdx.x, lane = tid & 63, w = tid >> 6;
  int r0 = lane & 15, g = lane >> 4;
  int trow = tid >> 4, tcol = tid & 15;

  const float* brow = (trow < 16)
      ? (B + (long long)(n0 + trow) * K)
      : (B + (long long)(4096 + n0 + trow - 16) * K);
  const float* bsrc = brow + tcol * 8;
  const u16* abase = A + (long long)(w * 32 + r0) * K + g * 8;
  int swr = (trow & 7) << 4;
  int wofs = trow * 256 + ((tcol * 16) ^ swr);

  {
    f32x4 u = *(const f32x4*)bsrc;
    f32x4 v = *(const f32x4*)(bsrc + 4);
    *(bf16x8*)&Bl[0][wofs] = cvt2(u, v);
  }
  bf16x8 a[2][2][4];
#pragma unroll
  for (int mi = 0; mi < 2; mi++)
#pragma unroll
    for (int kk = 0; kk < 4; kk++)
      a[0][mi][kk] = *(const bf16x8*)(abase + (long long)mi * 16 * K + kk * 32);

  f32x4 acc[2][2];
#pragma unroll
  for (int i = 0; i < 2; i++)
#pragma unroll
    for (int j = 0; j < 2; j++) acc[i][j] = (f32x4){0.f, 0.f, 0.f, 0.f};

  __syncthreads();

#pragma unroll
  for (int ibk = 0; ibk < NBK; ibk++) {
    const int cur = ibk & 1;
    const int nxt = cur ^ 1;
    f32x4 u, v;
    if (ibk + 1 < NBK) {
      int ko = (ibk + 1) * 128;
#pragma unroll
      for (int mi = 0; mi < 2; mi++)
#pragma unroll
        for (int kk = 0; kk < 4; kk++)
          a[nxt][mi][kk] = *(const bf16x8*)(abase + (long long)mi * 16 * K + ko + kk * 32);
      u = *(const f32x4*)(bsrc + ko);
      v = *(const f32x4*)(bsrc + ko + 4);
    }
    bf16x8 bfr[2][4];
#pragma unroll
    for (int nj = 0; nj < 2; nj++) {
      int row = nj * 16 + r0;
      int rb = row * 256, sw = (row & 7) << 4;
#pragma unroll
      for (int kk = 0; kk < 4; kk++)
        bfr[nj][kk] = *(const bf16x8*)&Bl[cur][rb + ((kk * 64 + g * 16) ^ sw)];
    }
#pragma unroll
    for (int kk = 0; kk < 4; kk++)
#pragma unroll
      for (int mi = 0; mi < 2; mi++)
#pragma unroll
        for (int nj = 0; nj < 2; nj++)
          acc[mi][nj] = __builtin_amdgcn_mfma_f32_16x16x32_bf16(a[cur][mi][kk], bfr[nj][kk], acc[mi][nj], 0, 0, 0);
    if (ibk + 1 < NBK)
      *(bf16x8*)&Bl[nxt][wofs] = cvt2(u, v);
    __syncthreads();
  }

  int rr = (lane >> 4) << 2;
#pragma unroll
  for (int mi = 0; mi < 2; mi++)
#pragma unroll
    for (int q = 0; q < 4; q++) {
      int row = w * 32 + mi * 16 + rr + q;
      float gv = acc[mi][0][q], uv = acc[mi][1][q];
      y[(long long)row * 4096 + n0 + r0] = f2bf((gv / (1.0f + __expf(-gv))) * uv);
    }
}

// ---------------- fused residual + rmsnorm (sum variant, no eps, no weight)
__global__ __launch_bounds__(256) void rms_fuse(const float* __restrict__ src,
                                                const float* __restrict__ parts, int np,
                                                float* __restrict__ hout, u16* __restrict__ x) {
  int s = blockIdx.x, tid = threadIdx.x;
  __shared__ float red[4];
  f32x4 hv = ((const f32x4*)(src + s * 1024))[tid];
  for (int p = 0; p < np; p++) {
    f32x4 pv = ((const f32x4*)(parts + (long long)p * 262144 + s * 1024))[tid];
    hv[0] += pv[0]; hv[1] += pv[1]; hv[2] += pv[2]; hv[3] += pv[3];
  }
  float ss = hv[0]*hv[0] + hv[1]*hv[1] + hv[2]*hv[2] + hv[3]*hv[3];
#pragma unroll
  for (int off = 32; off > 0; off >>= 1) ss += __shfl_xor(ss, off, 64);
  int lane = tid & 63, w = tid >> 6;
  if (lane == 0) red[w] = ss;
  __syncthreads();
  ss = red[0] + red[1] + red[2] + red[3];
  float r = 1.0f / sqrtf(ss);
  ((f32x4*)(hout + s * 1024))[tid] = hv;
  u16x4 o;
#pragma unroll
  for (int c = 0; c < 4; c++) o[c] = f2bf(hv[c] * r);
  ((u16x4*)x)[s * 256 + tid] = o;
}

// ---------------- final: h_new = h + sum(parts); out = h_new*rsqrt(mean+1e-6)*nw
__global__ __launch_bounds__(256) void final_fuse(const float* __restrict__ src,
                                                  const float* __restrict__ parts, int np,
                                                  const float* __restrict__ nw,
                                                  float* __restrict__ out) {
  int s = blockIdx.x, tid = threadIdx.x;
  __shared__ float red[4];
  f32x4 hv = ((const f32x4*)(src + s * 1024))[tid];
  for (int p = 0; p < np; p++) {
    f32x4 pv = ((const f32x4*)(parts + (long long)p * 262144 + s * 1024))[tid];
    hv[0] += pv[0]; hv[1] += pv[1]; hv[2] += pv[2]; hv[3] += pv[3];
  }
  float ss = hv[0]*hv[0] + hv[1]*hv[1] + hv[2]*hv[2] + hv[3]*hv[3];
#pragma unroll
  for (int off = 32; off > 0; off >>= 1) ss += __shfl_xor(ss, off, 64);
  int lane = tid & 63, w = tid >> 6;
  if (lane == 0) red[w] = ss;
  __syncthreads();
  ss = red[0] + red[1] + red[2] + red[3];
  float r = 1.0f / sqrtf(ss * (1.0f / 1024.0f) + 1e-6f);
  f32x4 wv = ((const f32x4*)nw)[tid];
  f32x4 o; o[0]=hv[0]*r*wv[0]; o[1]=hv[1]*r*wv[1]; o[2]=hv[2]*r*wv[2]; o[3]=hv[3]*r*wv[3];
  ((f32x4*)(out + s * 1024))[tid] = o;
}

// ---------------- transpose ALL layers' past K/V to bf16 MFMA layouts (once)
__global__ __launch_bounds__(256) void transpose_past(const float* __restrict__ pk,
                                                      const float* __restrict__ pv,
                                                      u16* __restrict__ Kb, u16* __restrict__ Vb) {
  __shared__ float tile[64][65];
  int t0 = blockIdx.x * 64;
  int kvh = blockIdx.y;
  int l = blockIdx.z >> 1, part = blockIdx.z & 1;
  int lk = l * 2 + kvh;
  int tid = threadIdx.x;
  if (part == 0) {
    const float* src = pk + (long long)lk * 64 * 2048;        // [d][t]
#pragma unroll
    for (int r = 0; r < 16; r++) {
      int idx = r * 256 + tid; int d = idx >> 6, t = idx & 63;
      tile[d][t] = src[d * 2048 + t0 + t];
    }
    __syncthreads();
    u16* dst = Kb + (long long)lk * 2304 * 64;                // [t][d]
#pragma unroll
    for (int r = 0; r < 16; r++) {
      int idx = r * 256 + tid; int t = idx >> 6, d = idx & 63;
      dst[(t0 + t) * 64 + d] = f2bf(tile[d][t]);
    }
  } else {
    const float* src = pv + (long long)lk * 2048 * 64;        // [t][d]
#pragma unroll
    for (int r = 0; r < 16; r++) {
      int idx = r * 256 + tid; int t = idx >> 6, d = idx & 63;
      tile[t][d] = src[(t0 + t) * 64 + d];
    }
    __syncthreads();
    u16* dst = Vb + (long long)lk * 64 * 2304;                // [d][t]
#pragma unroll
    for (int r = 0; r < 16; r++) {
      int idx = r * 256 + tid; int d = idx >> 6, t = idx & 63;
      dst[d * 2304 + t0 + t] = f2bf(tile[t][d]);
    }
  }
}

// ---------------- rope (sums 2 qkv partials) + scatter new q/k/v
__global__ __launch_bounds__(256) void rope_qkv(const float* __restrict__ P,
                                                const float* __restrict__ cs,
                                                const float* __restrict__ sn,
                                                u16* __restrict__ qb,
                                                u16* __restrict__ Kb,
                                                u16* __restrict__ Vb) {
  int s = blockIdx.x, tid = threadIdx.x;
  const float* p0 = P + (long long)s * 1280;
  const float* p1 = P + 327680 + (long long)s * 1280;
  for (int i = tid; i < 1280; i += 256) {
    int hh = i >> 6, d = i & 63;
    float v = p0[i] + p1[i];
    if (hh < 18) {
      int j = (hh << 6) | ((d + 32) & 63);
      float vr = p0[j] + p1[j];
      v = v * cs[s * 64 + d] + vr * sn[s * 64 + d];
      if (hh < 16) qb[hh * (256 * 64) + s * 64 + d] = f2bf(v);
      else         Kb[(hh - 16) * (2304 * 64) + (2048 + s) * 64 + d] = f2bf(v);
    } else {
      Vb[(hh - 18) * (64 * 2304) + d * 2304 + 2048 + s] = f2bf(v);
    }
  }
}

// ---------------- flash attention, swapped-operand form (verified)
struct KV { bf16x8 kf[2][2]; bf16x8 vf[4]; };

__global__ __launch_bounds__(256) void flash_attn(
    const u16* __restrict__ qb, const u16* __restrict__ Kb2,
    const u16* __restrict__ Vb2, u16* __restrict__ oacc)
{
  __shared__ u16 Plds[4][16][36];
  __shared__ float Osh[4][16][68];
  __shared__ float msh[4][16];
  __shared__ float lsh[4][16];

  int hh = blockIdx.y, kvh = hh >> 3;
  int s0 = blockIdx.x * 16;
  int tid = threadIdx.x, lane = tid & 63, w = tid >> 6;
  int g = lane >> 4, r0 = lane & 15;

  const u16* Q  = qb  + hh * (256 * 64);
  const u16* Kh = Kb2 + kvh * (2304 * 64);
  const u16* Vh = Vb2 + kvh * (64 * 2304);

  bf16x8 qf[2];
#pragma unroll
  for (int kk = 0; kk < 2; kk++)
    qf[kk] = *(const bf16x8*)(Q + (s0 + r0) * 64 + kk * 32 + g * 8);

  f32x4 O[4];
#pragma unroll
  for (int dj = 0; dj < 4; dj++) O[dj] = (f32x4){0.f, 0.f, 0.f, 0.f};
  float m = -1e30f, l = 0.f;

  int t0s = w * 576;

  auto loadkv = [&](KV& d, int t0) {
#pragma unroll
    for (int tj = 0; tj < 2; tj++)
#pragma unroll
      for (int kk = 0; kk < 2; kk++)
        d.kf[tj][kk] = *(const bf16x8*)(Kh + (t0 + tj * 16 + r0) * 64 + kk * 32 + g * 8);
#pragma unroll
    for (int dj = 0; dj < 4; dj++)
      d.vf[dj] = *(const bf16x8*)(Vh + (dj * 16 + r0) * 2304 + t0 + g * 8);
  };

  auto step = [&](KV& kv, int t0) {
    f32x4 sc[2];
#pragma unroll
    for (int tj = 0; tj < 2; tj++) {
      f32x4 z = (f32x4){0.f, 0.f, 0.f, 0.f};
      z = __builtin_amdgcn_mfma_f32_16x16x32_bf16(kv.kf[tj][0], qf[0], z, 0, 0, 0);
      z = __builtin_amdgcn_mfma_f32_16x16x32_bf16(kv.kf[tj][1], qf[1], z, 0, 0, 0);
      sc[tj] = z;
    }
    if (t0 + 31 > 2048 + s0) {
#pragma unroll
      for (int tj = 0; tj < 2; tj++)
#pragma unroll
        for (int q = 0; q < 4; q++) {
          int tg = t0 + tj * 16 + g * 4 + q;
          int sg = s0 + r0;
          if (tg > 2048 + sg) sc[tj][q] = -1e30f;
        }
    }
    float rm = -1e30f;
#pragma unroll
    for (int tj = 0; tj < 2; tj++)
#pragma unroll
      for (int q = 0; q < 4; q++) rm = fmaxf(rm, sc[tj][q]);
    rm = fmaxf(rm, __shfl_xor(rm, 16, 64));
    rm = fmaxf(rm, __shfl_xor(rm, 32, 64));
    float mn = fmaxf(m, rm);
    float sca = __expf(m - mn);
    float rs = 0.f;
#pragma unroll
    for (int tj = 0; tj < 2; tj++)
#pragma unroll
      for (int q = 0; q < 4; q++) {
        sc[tj][q] = __expf(sc[tj][q] - mn);
        rs += sc[tj][q];
      }
    rs += __shfl_xor(rs, 16, 64);
    rs += __shfl_xor(rs, 32, 64);
    l = l * sca + rs;
    m = mn;
#pragma unroll
    for (int dj = 0; dj < 4; dj++) {
      O[dj][0] *= sca; O[dj][1] *= sca; O[dj][2] *= sca; O[dj][3] *= sca;
    }
#pragma unroll
    for (int tj = 0; tj < 2; tj++) {
      u16x4 pw;
#pragma unroll
      for (int q = 0; q < 4; q++) pw[q] = f2bf(sc[tj][q]);
      *(u16x4*)&Plds[w][r0][tj * 16 + g * 4] = pw;
    }
    u16x4 plo = *(const u16x4*)&Plds[w][r0][g * 8];
    u16x4 phi = *(const u16x4*)&Plds[w][r0][g * 8 + 4];
    union { bf16x8 v; u16x4 h[2]; } pu;
    pu.h[0] = plo; pu.h[1] = phi;
#pragma unroll
    for (int dj = 0; dj < 4; dj++)
      O[dj] = __builtin_amdgcn_mfma_f32_16x16x32_bf16(kv.vf[dj], pu.v, O[dj], 0, 0, 0);
  };

  KV bufA, bufB;
  loadkv(bufA, t0s);
#pragma unroll 1
  for (int it = 0; it < 18; it += 2) {
    int t0 = t0s + it * 32;
    loadkv(bufB, t0 + 32);
    step(bufA, t0);
    if (it + 2 < 18) loadkv(bufA, t0 + 64);
    step(bufB, t0 + 32);
  }

#pragma unroll
  for (int dj = 0; dj < 4; dj++)
    *(f32x4*)&Osh[w][r0][dj * 16 + g * 4] = O[dj];
  if (g == 0) { msh[w][r0] = m; lsh[w][r0] = l; }
  __syncthreads();

  int row = tid >> 4, c0 = (tid & 15) * 4;
  float M = fmaxf(fmaxf(msh[0][row], msh[1][row]), fmaxf(msh[2][row], msh[3][row]));
  float L = 0.f;
  float a0 = 0.f, a1 = 0.f, a2 = 0.f, a3 = 0.f;
#pragma unroll
  for (int w4 = 0; w4 < 4; w4++) {
    float e = __expf(msh[w4][row] - M);
    L += lsh[w4][row] * e;
    f32x4 ov = *(const f32x4*)&Osh[w4][row][c0];
    a0 += e * ov[0]; a1 += e * ov[1]; a2 += e * ov[2]; a3 += e * ov[3];
  }
  float inv = 1.0f / L;
  u16x4 o4;
  o4[0] = f2bf(a0 * inv); o4[1] = f2bf(a1 * inv);
  o4[2] = f2bf(a2 * inv); o4[3] = f2bf(a3 * inv);
  *(u16x4*)(oacc + (long long)(s0 + row) * 1024 + hh * 64 + c0) = o4;
}

// ---------------- launch ----------------
extern "C" void kernel_launch(void* const* d_in, const int* in_sizes, int n_in,
                              void* d_out, int out_size, void* d_ws, size_t ws_size,
                              hipStream_t stream) {
  (void)in_sizes; (void)n_in; (void)out_size; (void)ws_size;
  const float* hs   = (const float*)d_in[0];
  const float* rc   = (const float*)d_in[1];
  const float* rs   = (const float*)d_in[2];
  const float* pk   = (const float*)d_in[4];
  const float* pv   = (const float*)d_in[5];
  const float* qkvw = (const float*)d_in[6];
  const float* ow   = (const float*)d_in[7];
  const float* guw  = (const float*)d_in[8];
  const float* dw   = (const float*)d_in[9];
  const float* nw   = (const float*)d_in[10];
  float* out = (float*)d_out;

  char* base = (char*)d_ws;
  float* h   = (float*)(base + 0);            // 1 MB
  u16*  x    = (u16*)(base + 1048576);        // 0.5 MB
  float* Pq  = (float*)(base + 1572864);      // 2.5 MB  [2][256][1280]
  float* Po  = (float*)(base + 4194304);      // 4 MB    [4][256][1024]
  float* Pd  = (float*)(base + 8388608);      // 8 MB    [8][256][1024]
  u16*  y    = (u16*)(base + 16777216);       // 2 MB    [256][4096] bf16
  u16*  oacc = (u16*)(base + 18874368);       // 0.5 MB
  u16*  qb   = (u16*)(base + 19398656);       // 0.5 MB
  u16*  Kb   = (u16*)(base + 19922944);       // 4.5 MB  [8][2][2304][64]
  u16*  Vb   = (u16*)(base + 24641536);       // 4.5 MB  [8][2][64][2304]

  transpose_past<<<dim3(32, 2, 16), 256, 0, stream>>>(pk, pv, Kb, Vb);

  for (int l = 0; l < 8; ++l) {
    u16* Kbl = Kb + (long long)l * 2 * 2304 * 64;
    u16* Vbl = Vb + (long long)l * 2 * 64 * 2304;

    if (l == 0)
      rms_fuse<<<256, 256, 0, stream>>>(hs, nullptr, 0, h, x);
    else
      rms_fuse<<<256, 256, 0, stream>>>(h, Pd, 8, h, x);

    gemmW<0, 4><<<dim3(40, 2), 512, 0, stream>>>(
        x, qkvw + (long long)l * 1310720, Pq, 1024, 1280);
    rope_qkv<<<256, 256, 0, stream>>>(Pq, rc, rs, qb, Kbl, Vbl);
    flash_attn<<<dim3(16, 16), 256, 0, stream>>>(qb, Kbl, Vbl, oacc);
    gemmW<0, 2><<<dim3(32, 4), 512, 0, stream>>>(
        oacc, ow + (long long)l * 1048576, Po, 1024, 1024);
    rms_fuse<<<256, 256, 0, stream>>>(h, Po, 4, h, x);
    gemmGU<<<dim3(256, 1), 512, 0, stream>>>(
        x, guw + (long long)l * 8388608, y);
    gemmW<0, 4><<<dim3(32, 8), 512, 0, stream>>>(
        y, dw + (long long)l * 4194304, Pd, 4096, 1024);
  }
  final_fuse<<<256, 256, 0, stream>>>(h, Pd, 8, nw, out);
}